// Round 1
// baseline (370.255 us; speedup 1.0000x reference)
//
#include <hip/hip_runtime.h>
#include <hip/hip_bf16.h>

#define N_NODES 50000
#define FDIM 128

// ---------------------------------------------------------------------------
// CSR build: count in-degree per dst
// ---------------------------------------------------------------------------
__global__ __launch_bounds__(256) void count_kernel(const int* __restrict__ dst,
                                                    int* __restrict__ counts, int E) {
    int e = blockIdx.x * blockDim.x + threadIdx.x;
    if (e < E) atomicAdd(&counts[dst[e]], 1);
}

__global__ __launch_bounds__(256) void dinv_kernel(const int* __restrict__ counts,
                                                   float* __restrict__ dinv, int n) {
    int v = blockIdx.x * blockDim.x + threadIdx.x;
    if (v < n) dinv[v] = rsqrtf((float)counts[v] + 1.0f);  // +1 = self-loop
}

// Single-block exclusive scan over counts -> offsets[0..n], cursor copy
__global__ __launch_bounds__(1024) void scan_kernel(const int* __restrict__ counts,
                                                    int* __restrict__ offsets,
                                                    int* __restrict__ cursor, int n) {
    __shared__ int buf[1024];
    __shared__ int carry_s;
    int t = threadIdx.x;
    if (t == 0) carry_s = 0;
    __syncthreads();
    for (int base = 0; base < n; base += 1024) {
        int i = base + t;
        int v = (i < n) ? counts[i] : 0;
        buf[t] = v;
        __syncthreads();
        for (int off = 1; off < 1024; off <<= 1) {
            int add = (t >= off) ? buf[t - off] : 0;
            __syncthreads();
            buf[t] += add;
            __syncthreads();
        }
        int incl = buf[t];
        int carry = carry_s;
        int excl = carry + incl - v;
        if (i < n) { offsets[i] = excl; cursor[i] = excl; }
        __syncthreads();
        if (t == 1023) carry_s = carry + incl;
        __syncthreads();
    }
    if (t == 0) offsets[n] = carry_s;
}

__global__ __launch_bounds__(256) void scatter_kernel(const int* __restrict__ src,
                                                      const int* __restrict__ dst,
                                                      const float* __restrict__ dinv,
                                                      int* __restrict__ cursor,
                                                      int* __restrict__ csr_src,
                                                      float* __restrict__ csr_w, int E) {
    int e = blockIdx.x * blockDim.x + threadIdx.x;
    if (e < E) {
        int s = src[e], d = dst[e];
        float w = dinv[s] * dinv[d];
        int pos = atomicAdd(&cursor[d], 1);
        csr_src[pos] = s;
        csr_w[pos]   = w;
    }
}

// ---------------------------------------------------------------------------
// Aggregation: Y[v] = dinv[v]^2 * X[v] + sum_e w_e * X[src_e]   (128-wide)
// one wave per node, float2 per lane
// ---------------------------------------------------------------------------
__global__ __launch_bounds__(256) void agg_kernel(const float* __restrict__ X,
                                                  const int* __restrict__ offsets,
                                                  const int* __restrict__ csr_src,
                                                  const float* __restrict__ csr_w,
                                                  const float* __restrict__ dinv,
                                                  float* __restrict__ Y, int n) {
    int wave = blockIdx.x * (blockDim.x >> 6) + (threadIdx.x >> 6);
    int lane = threadIdx.x & 63;
    if (wave >= n) return;
    int v = wave;
    float dv = dinv[v];
    float self_w = dv * dv;
    float2 xv = ((const float2*)(X + (size_t)v * FDIM))[lane];
    float2 acc;
    acc.x = self_w * xv.x;
    acc.y = self_w * xv.y;
    int beg = offsets[v], end = offsets[v + 1];
    int i = beg;
    // 2-deep unroll for latency hiding
    for (; i + 1 < end; i += 2) {
        int   s0 = csr_src[i],     s1 = csr_src[i + 1];
        float w0 = csr_w[i],       w1 = csr_w[i + 1];
        float2 m0 = ((const float2*)(X + (size_t)s0 * FDIM))[lane];
        float2 m1 = ((const float2*)(X + (size_t)s1 * FDIM))[lane];
        acc.x += w0 * m0.x + w1 * m1.x;
        acc.y += w0 * m0.y + w1 * m1.y;
    }
    if (i < end) {
        int s = csr_src[i];
        float w = csr_w[i];
        float2 m = ((const float2*)(X + (size_t)s * FDIM))[lane];
        acc.x += w * m.x;
        acc.y += w * m.y;
    }
    ((float2*)(Y + (size_t)v * FDIM))[lane] = acc;
}

// ---------------------------------------------------------------------------
// GEMM: C[M,128] = A[M,128] @ W[128,128] (+bias, epilogue variants)
// EPI=0: relu(. + b1) -> C row-major [M,128]
// EPI=1: cols 0..63 -> d_out[row*64+c] + b_mu;  cols 64..127 -> d_out[M*64 + row*64 + c-64] + b_logstd
// 64-row tile per block, 256 threads, thread = 8 rows x 4 cols
// ---------------------------------------------------------------------------
template <int EPI>
__global__ __launch_bounds__(256) void gemm128(const float* __restrict__ A,
                                               const float* __restrict__ Wa,
                                               const float* __restrict__ Wb,
                                               const float* __restrict__ ba,
                                               const float* __restrict__ bb,
                                               float* __restrict__ C, int M) {
    __shared__ float As[64][36];    // 32-k chunk, padded (16B-aligned rows)
    __shared__ float Ws[32][132];   // 32-k x 128 cols, padded

    int t  = threadIdx.x;
    int tx = t & 31;   // col quad: cols tx*4..tx*4+3
    int ty = t >> 5;   // row group: rows ty*8..ty*8+7
    int row0 = blockIdx.x * 64;

    float acc[8][4];
#pragma unroll
    for (int i = 0; i < 8; i++)
#pragma unroll
        for (int j = 0; j < 4; j++) acc[i][j] = 0.f;

    for (int kc = 0; kc < 128; kc += 32) {
        // stage A chunk [64][32]
        {
            int r  = t >> 2;   // 0..63
            int c4 = t & 3;    // 0..3
#pragma unroll
            for (int p = 0; p < 2; p++) {
                int cc = c4 + p * 4;  // float4 index 0..7
                float4 v = make_float4(0.f, 0.f, 0.f, 0.f);
                int gr = row0 + r;
                if (gr < M) v = *(const float4*)(A + (size_t)gr * FDIM + kc + cc * 4);
                *(float4*)&As[r][cc * 4] = v;
            }
        }
        // stage W chunk [32][128]
        {
            int kr = t >> 3;   // 0..31
            int c4 = t & 7;    // 0..7
#pragma unroll
            for (int p = 0; p < 4; p++) {
                int cc  = c4 + p * 8;  // float4 col 0..31
                int col = cc * 4;
                float4 w;
                if (EPI == 0) {
                    w = *(const float4*)(Wa + (size_t)(kc + kr) * 128 + col);
                } else {
                    if (col < 64) w = *(const float4*)(Wa + (size_t)(kc + kr) * 64 + col);
                    else          w = *(const float4*)(Wb + (size_t)(kc + kr) * 64 + (col - 64));
                }
                *(float4*)&Ws[kr][col] = w;
            }
        }
        __syncthreads();
#pragma unroll 8
        for (int k = 0; k < 32; k++) {
            float4 w = *(const float4*)&Ws[k][tx * 4];
#pragma unroll
            for (int i = 0; i < 8; i++) {
                float a = As[ty * 8 + i][k];
                acc[i][0] += a * w.x;
                acc[i][1] += a * w.y;
                acc[i][2] += a * w.z;
                acc[i][3] += a * w.w;
            }
        }
        __syncthreads();
    }

    int col = tx * 4;
    if (EPI == 0) {
        float4 b = *(const float4*)(ba + col);
#pragma unroll
        for (int i = 0; i < 8; i++) {
            int gr = row0 + ty * 8 + i;
            if (gr < M) {
                float4 o;
                o.x = fmaxf(acc[i][0] + b.x, 0.f);
                o.y = fmaxf(acc[i][1] + b.y, 0.f);
                o.z = fmaxf(acc[i][2] + b.z, 0.f);
                o.w = fmaxf(acc[i][3] + b.w, 0.f);
                *(float4*)(C + (size_t)gr * FDIM + col) = o;
            }
        }
    } else {
        bool is_mu = (col < 64);
        int c2 = is_mu ? col : (col - 64);
        const float* bp = is_mu ? ba : bb;
        float4 b = *(const float4*)(bp + c2);
        size_t base = is_mu ? 0 : (size_t)M * 64;
#pragma unroll
        for (int i = 0; i < 8; i++) {
            int gr = row0 + ty * 8 + i;
            if (gr < M) {
                float4 o;
                o.x = acc[i][0] + b.x;
                o.y = acc[i][1] + b.y;
                o.z = acc[i][2] + b.z;
                o.w = acc[i][3] + b.w;
                *(float4*)(C + base + (size_t)gr * 64 + c2) = o;
            }
        }
    }
}

// ---------------------------------------------------------------------------
extern "C" void kernel_launch(void* const* d_in, const int* in_sizes, int n_in,
                              void* d_out, int out_size, void* d_ws, size_t ws_size,
                              hipStream_t stream) {
    const float* x    = (const float*)d_in[0];
    const int*   ei   = (const int*)d_in[1];
    const float* W1   = (const float*)d_in[2];
    const float* b1   = (const float*)d_in[3];
    const float* Wmu  = (const float*)d_in[4];
    const float* bmu  = (const float*)d_in[5];
    const float* Wlog = (const float*)d_in[6];
    const float* blog = (const float*)d_in[7];
    float* out = (float*)d_out;

    const int N = N_NODES;
    const int E = in_sizes[1] / 2;
    const int* src = ei;
    const int* dst = ei + E;

    // workspace layout (256B aligned)
    auto align256 = [](size_t x) { return (x + 255) & ~(size_t)255; };
    char* ws = (char*)d_ws;
    size_t off = 0;
    int*   counts  = (int*)(ws + off);  off += align256((size_t)N * 4);
    int*   cursor  = (int*)(ws + off);  off += align256((size_t)N * 4);
    int*   offsets = (int*)(ws + off);  off += align256((size_t)(N + 1) * 4);
    float* dinv    = (float*)(ws + off); off += align256((size_t)N * 4);
    int*   csr_src = (int*)(ws + off);  off += align256((size_t)E * 4);
    float* csr_w   = (float*)(ws + off); off += align256((size_t)E * 4);
    float* bufA    = (float*)(ws + off); off += align256((size_t)N * FDIM * 4);
    float* bufB    = (float*)(ws + off); off += align256((size_t)N * FDIM * 4);

    // 1. build CSR + dinv
    hipMemsetAsync(counts, 0, (size_t)N * 4, stream);
    count_kernel<<<(E + 255) / 256, 256, 0, stream>>>(dst, counts, E);
    dinv_kernel<<<(N + 255) / 256, 256, 0, stream>>>(counts, dinv, N);
    scan_kernel<<<1, 1024, 0, stream>>>(counts, offsets, cursor, N);
    scatter_kernel<<<(E + 255) / 256, 256, 0, stream>>>(src, dst, dinv, cursor,
                                                        csr_src, csr_w, E);

    // 2. ax = A @ x   (aggregate raw features; A(xW) == (Ax)W)
    int agg_blocks = (N + 3) / 4;  // 4 waves (nodes) per 256-thread block
    agg_kernel<<<agg_blocks, 256, 0, stream>>>(x, offsets, csr_src, csr_w, dinv, bufA, N);

    // 3. h1 = relu(ax @ W1 + b1)
    gemm128<0><<<(N + 63) / 64, 256, 0, stream>>>(bufA, W1, nullptr, b1, nullptr, bufB, N);

    // 4. ah = A @ h1
    agg_kernel<<<agg_blocks, 256, 0, stream>>>(bufB, offsets, csr_src, csr_w, dinv, bufA, N);

    // 5. [mu | logstd] = ah @ [Wmu | Wlog] + [bmu | blog] -> d_out (split halves)
    gemm128<1><<<(N + 63) / 64, 256, 0, stream>>>(bufA, Wmu, Wlog, bmu, blog, out, N);
}

// Round 2
// 288.001 us; speedup vs baseline: 1.2856x; 1.2856x over previous
//
#include <hip/hip_runtime.h>
#include <hip/hip_bf16.h>

#define N_NODES 50000
#define FDIM 128
#define NPAD 50176      // 49 * 1024, covers N_NODES+1
#define SCAN_NB 49      // blocks in hierarchical scan

// ---------------------------------------------------------------------------
// CSR build: count in-degree per dst
// ---------------------------------------------------------------------------
__global__ __launch_bounds__(256) void count_kernel(const int* __restrict__ dst,
                                                    int* __restrict__ counts, int E) {
    int e = blockIdx.x * blockDim.x + threadIdx.x;
    if (e < E) atomicAdd(&counts[dst[e]], 1);
}

__global__ __launch_bounds__(256) void dinv_kernel(const int* __restrict__ counts,
                                                   float* __restrict__ dinv, int n) {
    int v = blockIdx.x * blockDim.x + threadIdx.x;
    if (v < n) dinv[v] = rsqrtf((float)counts[v] + 1.0f);  // +1 = self-loop
}

// ---------------------------------------------------------------------------
// Hierarchical exclusive scan over counts[NPAD] (pad is zeroed).
// k1: per-block (1024 elems) local exclusive scan + block sums
// k2: one wave scans the 49 block sums -> block offsets
// k3: add block offset, write offsets + cursor
// ---------------------------------------------------------------------------
__global__ __launch_bounds__(256) void scan_local_kernel(const int* __restrict__ counts,
                                                         int* __restrict__ local,
                                                         int* __restrict__ bsums) {
    int t    = threadIdx.x;
    int lane = t & 63;
    int wid  = t >> 6;
    int base = blockIdx.x * 1024 + t * 4;
    int4 v = *(const int4*)(counts + base);
    int s = v.x + v.y + v.z + v.w;
    int incl = s;
#pragma unroll
    for (int off = 1; off < 64; off <<= 1) {
        int u = __shfl_up(incl, off, 64);
        if (lane >= off) incl += u;
    }
    __shared__ int wtot[4];
    if (lane == 63) wtot[wid] = incl;
    __syncthreads();
    int wbase = 0;
#pragma unroll
    for (int w = 0; w < 3; w++) wbase += (w < wid) ? wtot[w] : 0;
    int excl = wbase + incl - s;
    int4 o;
    o.x = excl;
    o.y = excl + v.x;
    o.z = o.y + v.y;
    o.w = o.z + v.z;
    *(int4*)(local + base) = o;
    if (t == 255) bsums[blockIdx.x] = wbase + incl;  // block total
}

__global__ __launch_bounds__(64) void scan_bsums_kernel(const int* __restrict__ bsums,
                                                        int* __restrict__ boffs, int nb) {
    int lane = threadIdx.x;
    int v = (lane < nb) ? bsums[lane] : 0;
    int incl = v;
#pragma unroll
    for (int off = 1; off < 64; off <<= 1) {
        int u = __shfl_up(incl, off, 64);
        if (lane >= off) incl += u;
    }
    if (lane < nb) boffs[lane] = incl - v;  // exclusive
}

__global__ __launch_bounds__(256) void scan_add_kernel(const int* __restrict__ local,
                                                       const int* __restrict__ boffs,
                                                       int* __restrict__ offsets,
                                                       int* __restrict__ cursor) {
    int base = blockIdx.x * 1024 + threadIdx.x * 4;
    int bo = boffs[blockIdx.x];
    int4 v = *(const int4*)(local + base);
    v.x += bo; v.y += bo; v.z += bo; v.w += bo;
    *(int4*)(offsets + base) = v;
    *(int4*)(cursor + base)  = v;
}

__global__ __launch_bounds__(256) void scatter_kernel(const int* __restrict__ src,
                                                      const int* __restrict__ dst,
                                                      const float* __restrict__ dinv,
                                                      int* __restrict__ cursor,
                                                      int* __restrict__ csr_src,
                                                      float* __restrict__ csr_w, int E) {
    int e = blockIdx.x * blockDim.x + threadIdx.x;
    if (e < E) {
        int s = src[e], d = dst[e];
        float w = dinv[s] * dinv[d];
        int pos = atomicAdd(&cursor[d], 1);
        csr_src[pos] = s;
        csr_w[pos]   = w;
    }
}

// ---------------------------------------------------------------------------
// Aggregation: Y[v] = dinv[v]^2 * X[v] + sum_e w_e * X[src_e]   (128-wide)
// one wave per node, float2 per lane
// ---------------------------------------------------------------------------
__global__ __launch_bounds__(256) void agg_kernel(const float* __restrict__ X,
                                                  const int* __restrict__ offsets,
                                                  const int* __restrict__ csr_src,
                                                  const float* __restrict__ csr_w,
                                                  const float* __restrict__ dinv,
                                                  float* __restrict__ Y, int n) {
    int wave = blockIdx.x * (blockDim.x >> 6) + (threadIdx.x >> 6);
    int lane = threadIdx.x & 63;
    if (wave >= n) return;
    int v = wave;
    float dv = dinv[v];
    float self_w = dv * dv;
    float2 xv = ((const float2*)(X + (size_t)v * FDIM))[lane];
    float2 acc;
    acc.x = self_w * xv.x;
    acc.y = self_w * xv.y;
    int beg = offsets[v], end = offsets[v + 1];
    int i = beg;
    for (; i + 1 < end; i += 2) {
        int   s0 = csr_src[i],     s1 = csr_src[i + 1];
        float w0 = csr_w[i],       w1 = csr_w[i + 1];
        float2 m0 = ((const float2*)(X + (size_t)s0 * FDIM))[lane];
        float2 m1 = ((const float2*)(X + (size_t)s1 * FDIM))[lane];
        acc.x += w0 * m0.x + w1 * m1.x;
        acc.y += w0 * m0.y + w1 * m1.y;
    }
    if (i < end) {
        int s = csr_src[i];
        float w = csr_w[i];
        float2 m = ((const float2*)(X + (size_t)s * FDIM))[lane];
        acc.x += w * m.x;
        acc.y += w * m.y;
    }
    ((float2*)(Y + (size_t)v * FDIM))[lane] = acc;
}

// ---------------------------------------------------------------------------
// GEMM: C[M,128] = A[M,128] @ W[128,128] (+bias, epilogue variants)
// ---------------------------------------------------------------------------
template <int EPI>
__global__ __launch_bounds__(256) void gemm128(const float* __restrict__ A,
                                               const float* __restrict__ Wa,
                                               const float* __restrict__ Wb,
                                               const float* __restrict__ ba,
                                               const float* __restrict__ bb,
                                               float* __restrict__ C, int M) {
    __shared__ float As[64][36];
    __shared__ float Ws[32][132];

    int t  = threadIdx.x;
    int tx = t & 31;
    int ty = t >> 5;
    int row0 = blockIdx.x * 64;

    float acc[8][4];
#pragma unroll
    for (int i = 0; i < 8; i++)
#pragma unroll
        for (int j = 0; j < 4; j++) acc[i][j] = 0.f;

    for (int kc = 0; kc < 128; kc += 32) {
        {
            int r  = t >> 2;
            int c4 = t & 3;
#pragma unroll
            for (int p = 0; p < 2; p++) {
                int cc = c4 + p * 4;
                float4 v = make_float4(0.f, 0.f, 0.f, 0.f);
                int gr = row0 + r;
                if (gr < M) v = *(const float4*)(A + (size_t)gr * FDIM + kc + cc * 4);
                *(float4*)&As[r][cc * 4] = v;
            }
        }
        {
            int kr = t >> 3;
            int c4 = t & 7;
#pragma unroll
            for (int p = 0; p < 4; p++) {
                int cc  = c4 + p * 8;
                int col = cc * 4;
                float4 w;
                if (EPI == 0) {
                    w = *(const float4*)(Wa + (size_t)(kc + kr) * 128 + col);
                } else {
                    if (col < 64) w = *(const float4*)(Wa + (size_t)(kc + kr) * 64 + col);
                    else          w = *(const float4*)(Wb + (size_t)(kc + kr) * 64 + (col - 64));
                }
                *(float4*)&Ws[kr][col] = w;
            }
        }
        __syncthreads();
#pragma unroll 8
        for (int k = 0; k < 32; k++) {
            float4 w = *(const float4*)&Ws[k][tx * 4];
#pragma unroll
            for (int i = 0; i < 8; i++) {
                float a = As[ty * 8 + i][k];
                acc[i][0] += a * w.x;
                acc[i][1] += a * w.y;
                acc[i][2] += a * w.z;
                acc[i][3] += a * w.w;
            }
        }
        __syncthreads();
    }

    int col = tx * 4;
    if (EPI == 0) {
        float4 b = *(const float4*)(ba + col);
#pragma unroll
        for (int i = 0; i < 8; i++) {
            int gr = row0 + ty * 8 + i;
            if (gr < M) {
                float4 o;
                o.x = fmaxf(acc[i][0] + b.x, 0.f);
                o.y = fmaxf(acc[i][1] + b.y, 0.f);
                o.z = fmaxf(acc[i][2] + b.z, 0.f);
                o.w = fmaxf(acc[i][3] + b.w, 0.f);
                *(float4*)(C + (size_t)gr * FDIM + col) = o;
            }
        }
    } else {
        bool is_mu = (col < 64);
        int c2 = is_mu ? col : (col - 64);
        const float* bp = is_mu ? ba : bb;
        float4 b = *(const float4*)(bp + c2);
        size_t base = is_mu ? 0 : (size_t)M * 64;
#pragma unroll
        for (int i = 0; i < 8; i++) {
            int gr = row0 + ty * 8 + i;
            if (gr < M) {
                float4 o;
                o.x = acc[i][0] + b.x;
                o.y = acc[i][1] + b.y;
                o.z = acc[i][2] + b.z;
                o.w = acc[i][3] + b.w;
                *(float4*)(C + base + (size_t)gr * 64 + c2) = o;
            }
        }
    }
}

// ---------------------------------------------------------------------------
extern "C" void kernel_launch(void* const* d_in, const int* in_sizes, int n_in,
                              void* d_out, int out_size, void* d_ws, size_t ws_size,
                              hipStream_t stream) {
    const float* x    = (const float*)d_in[0];
    const int*   ei   = (const int*)d_in[1];
    const float* W1   = (const float*)d_in[2];
    const float* b1   = (const float*)d_in[3];
    const float* Wmu  = (const float*)d_in[4];
    const float* bmu  = (const float*)d_in[5];
    const float* Wlog = (const float*)d_in[6];
    const float* blog = (const float*)d_in[7];
    float* out = (float*)d_out;

    const int N = N_NODES;
    const int E = in_sizes[1] / 2;
    const int* src = ei;
    const int* dst = ei + E;

    auto align256 = [](size_t x) { return (x + 255) & ~(size_t)255; };
    char* ws = (char*)d_ws;
    size_t off = 0;
    int*   counts  = (int*)(ws + off);  off += align256((size_t)NPAD * 4);
    int*   cursor  = (int*)(ws + off);  off += align256((size_t)NPAD * 4);
    int*   offsets = (int*)(ws + off);  off += align256((size_t)NPAD * 4);
    int*   local   = (int*)(ws + off);  off += align256((size_t)NPAD * 4);
    int*   bsums   = (int*)(ws + off);  off += align256(256 * 4);
    int*   boffs   = (int*)(ws + off);  off += align256(256 * 4);
    float* dinv    = (float*)(ws + off); off += align256((size_t)N * 4);
    int*   csr_src = (int*)(ws + off);  off += align256((size_t)E * 4);
    float* csr_w   = (float*)(ws + off); off += align256((size_t)E * 4);
    float* bufA    = (float*)(ws + off); off += align256((size_t)N * FDIM * 4);
    float* bufB    = (float*)(ws + off); off += align256((size_t)N * FDIM * 4);

    // 1. build CSR + dinv
    hipMemsetAsync(counts, 0, (size_t)NPAD * 4, stream);
    count_kernel<<<(E + 255) / 256, 256, 0, stream>>>(dst, counts, E);
    dinv_kernel<<<(N + 255) / 256, 256, 0, stream>>>(counts, dinv, N);
    scan_local_kernel<<<SCAN_NB, 256, 0, stream>>>(counts, local, bsums);
    scan_bsums_kernel<<<1, 64, 0, stream>>>(bsums, boffs, SCAN_NB);
    scan_add_kernel<<<SCAN_NB, 256, 0, stream>>>(local, boffs, offsets, cursor);
    scatter_kernel<<<(E + 255) / 256, 256, 0, stream>>>(src, dst, dinv, cursor,
                                                        csr_src, csr_w, E);

    // 2. ax = A @ x
    int agg_blocks = (N + 3) / 4;
    agg_kernel<<<agg_blocks, 256, 0, stream>>>(x, offsets, csr_src, csr_w, dinv, bufA, N);

    // 3. h1 = relu(ax @ W1 + b1)
    gemm128<0><<<(N + 63) / 64, 256, 0, stream>>>(bufA, W1, nullptr, b1, nullptr, bufB, N);

    // 4. ah = A @ h1
    agg_kernel<<<agg_blocks, 256, 0, stream>>>(bufB, offsets, csr_src, csr_w, dinv, bufA, N);

    // 5. [mu | logstd] -> d_out
    gemm128<1><<<(N + 63) / 64, 256, 0, stream>>>(bufA, Wmu, Wlog, bmu, blog, out, N);
}

// Round 3
// 274.532 us; speedup vs baseline: 1.3487x; 1.0491x over previous
//
#include <hip/hip_runtime.h>
#include <hip/hip_bf16.h>

#define N_NODES 50000
#define FDIM 128
#define NPAD 50176      // 49 * 1024, covers N_NODES+1
#define SCAN_NB 49      // blocks in hierarchical scan

// ---------------------------------------------------------------------------
// CSR build: count in-degree per dst
// ---------------------------------------------------------------------------
__global__ __launch_bounds__(256) void count_kernel(const int* __restrict__ dst,
                                                    int* __restrict__ counts, int E) {
    int e = blockIdx.x * blockDim.x + threadIdx.x;
    if (e < E) atomicAdd(&counts[dst[e]], 1);
}

__global__ __launch_bounds__(256) void dinv_kernel(const int* __restrict__ counts,
                                                   float* __restrict__ dinv, int n) {
    int v = blockIdx.x * blockDim.x + threadIdx.x;
    if (v < n) dinv[v] = rsqrtf((float)counts[v] + 1.0f);  // +1 = self-loop
}

// ---------------------------------------------------------------------------
// Hierarchical exclusive scan over counts[NPAD] (pad is zeroed).
// ---------------------------------------------------------------------------
__global__ __launch_bounds__(256) void scan_local_kernel(const int* __restrict__ counts,
                                                         int* __restrict__ local,
                                                         int* __restrict__ bsums) {
    int t    = threadIdx.x;
    int lane = t & 63;
    int wid  = t >> 6;
    int base = blockIdx.x * 1024 + t * 4;
    int4 v = *(const int4*)(counts + base);
    int s = v.x + v.y + v.z + v.w;
    int incl = s;
#pragma unroll
    for (int off = 1; off < 64; off <<= 1) {
        int u = __shfl_up(incl, off, 64);
        if (lane >= off) incl += u;
    }
    __shared__ int wtot[4];
    if (lane == 63) wtot[wid] = incl;
    __syncthreads();
    int wbase = 0;
#pragma unroll
    for (int w = 0; w < 3; w++) wbase += (w < wid) ? wtot[w] : 0;
    int excl = wbase + incl - s;
    int4 o;
    o.x = excl;
    o.y = excl + v.x;
    o.z = o.y + v.y;
    o.w = o.z + v.z;
    *(int4*)(local + base) = o;
    if (t == 255) bsums[blockIdx.x] = wbase + incl;  // block total
}

__global__ __launch_bounds__(64) void scan_bsums_kernel(const int* __restrict__ bsums,
                                                        int* __restrict__ boffs, int nb) {
    int lane = threadIdx.x;
    int v = (lane < nb) ? bsums[lane] : 0;
    int incl = v;
#pragma unroll
    for (int off = 1; off < 64; off <<= 1) {
        int u = __shfl_up(incl, off, 64);
        if (lane >= off) incl += u;
    }
    if (lane < nb) boffs[lane] = incl - v;  // exclusive
}

__global__ __launch_bounds__(256) void scan_add_kernel(const int* __restrict__ local,
                                                       const int* __restrict__ boffs,
                                                       int* __restrict__ offsets,
                                                       int* __restrict__ cursor) {
    int base = blockIdx.x * 1024 + threadIdx.x * 4;
    int bo = boffs[blockIdx.x];
    int4 v = *(const int4*)(local + base);
    v.x += bo; v.y += bo; v.z += bo; v.w += bo;
    *(int4*)(offsets + base) = v;
    *(int4*)(cursor + base)  = v;
}

// Edge record: {src, weight-as-int} packed 8B
__global__ __launch_bounds__(256) void scatter_kernel(const int* __restrict__ src,
                                                      const int* __restrict__ dst,
                                                      const float* __restrict__ dinv,
                                                      int* __restrict__ cursor,
                                                      int2* __restrict__ csr_ew, int E) {
    int e = blockIdx.x * blockDim.x + threadIdx.x;
    if (e < E) {
        int s = src[e], d = dst[e];
        float w = dinv[s] * dinv[d];
        int pos = atomicAdd(&cursor[d], 1);
        csr_ew[pos] = make_int2(s, __float_as_int(w));
    }
}

// ---------------------------------------------------------------------------
// Aggregation: Y[v] = dinv[v]^2 * X[v] + sum_e w_e * X[src_e]   (128-wide)
// HALF-WAVE per node: 32 lanes x float4 = 512B row. 2 nodes/wave -> 2
// independent edge loops co-issue; unroll 4 -> up to 8 gathers in flight.
// ---------------------------------------------------------------------------
__global__ __launch_bounds__(256) void agg_kernel(const float* __restrict__ X,
                                                  const int* __restrict__ offsets,
                                                  const int2* __restrict__ csr_ew,
                                                  const float* __restrict__ dinv,
                                                  float* __restrict__ Y, int n) {
    int node   = blockIdx.x * (blockDim.x >> 5) + (threadIdx.x >> 5);
    int lane32 = threadIdx.x & 31;
    if (node >= n) return;

    const float4* X4 = (const float4*)X;
    float dv = dinv[node];
    float self_w = dv * dv;
    float4 xv = X4[(size_t)node * 32 + lane32];
    float4 acc;
    acc.x = self_w * xv.x;
    acc.y = self_w * xv.y;
    acc.z = self_w * xv.z;
    acc.w = self_w * xv.w;

    int beg = offsets[node], end = offsets[node + 1];
    int i = beg;
    for (; i + 4 <= end; i += 4) {
        int2 e0 = csr_ew[i];
        int2 e1 = csr_ew[i + 1];
        int2 e2 = csr_ew[i + 2];
        int2 e3 = csr_ew[i + 3];
        float4 m0 = X4[(size_t)e0.x * 32 + lane32];
        float4 m1 = X4[(size_t)e1.x * 32 + lane32];
        float4 m2 = X4[(size_t)e2.x * 32 + lane32];
        float4 m3 = X4[(size_t)e3.x * 32 + lane32];
        float w0 = __int_as_float(e0.y), w1 = __int_as_float(e1.y);
        float w2 = __int_as_float(e2.y), w3 = __int_as_float(e3.y);
        acc.x += w0 * m0.x + w1 * m1.x + w2 * m2.x + w3 * m3.x;
        acc.y += w0 * m0.y + w1 * m1.y + w2 * m2.y + w3 * m3.y;
        acc.z += w0 * m0.z + w1 * m1.z + w2 * m2.z + w3 * m3.z;
        acc.w += w0 * m0.w + w1 * m1.w + w2 * m2.w + w3 * m3.w;
    }
    for (; i < end; i++) {
        int2 e = csr_ew[i];
        float w = __int_as_float(e.y);
        float4 m = X4[(size_t)e.x * 32 + lane32];
        acc.x += w * m.x;
        acc.y += w * m.y;
        acc.z += w * m.z;
        acc.w += w * m.w;
    }
    ((float4*)Y)[(size_t)node * 32 + lane32] = acc;
}

// ---------------------------------------------------------------------------
// GEMM: C[M,128] = A[M,128] @ W[128,128] (+bias, epilogue variants)
// ---------------------------------------------------------------------------
template <int EPI>
__global__ __launch_bounds__(256) void gemm128(const float* __restrict__ A,
                                               const float* __restrict__ Wa,
                                               const float* __restrict__ Wb,
                                               const float* __restrict__ ba,
                                               const float* __restrict__ bb,
                                               float* __restrict__ C, int M) {
    __shared__ float As[64][36];
    __shared__ float Ws[32][132];

    int t  = threadIdx.x;
    int tx = t & 31;
    int ty = t >> 5;
    int row0 = blockIdx.x * 64;

    float acc[8][4];
#pragma unroll
    for (int i = 0; i < 8; i++)
#pragma unroll
        for (int j = 0; j < 4; j++) acc[i][j] = 0.f;

    for (int kc = 0; kc < 128; kc += 32) {
        {
            int r  = t >> 2;
            int c4 = t & 3;
#pragma unroll
            for (int p = 0; p < 2; p++) {
                int cc = c4 + p * 4;
                float4 v = make_float4(0.f, 0.f, 0.f, 0.f);
                int gr = row0 + r;
                if (gr < M) v = *(const float4*)(A + (size_t)gr * FDIM + kc + cc * 4);
                *(float4*)&As[r][cc * 4] = v;
            }
        }
        {
            int kr = t >> 3;
            int c4 = t & 7;
#pragma unroll
            for (int p = 0; p < 4; p++) {
                int cc  = c4 + p * 8;
                int col = cc * 4;
                float4 w;
                if (EPI == 0) {
                    w = *(const float4*)(Wa + (size_t)(kc + kr) * 128 + col);
                } else {
                    if (col < 64) w = *(const float4*)(Wa + (size_t)(kc + kr) * 64 + col);
                    else          w = *(const float4*)(Wb + (size_t)(kc + kr) * 64 + (col - 64));
                }
                *(float4*)&Ws[kr][col] = w;
            }
        }
        __syncthreads();
#pragma unroll 8
        for (int k = 0; k < 32; k++) {
            float4 w = *(const float4*)&Ws[k][tx * 4];
#pragma unroll
            for (int i = 0; i < 8; i++) {
                float a = As[ty * 8 + i][k];
                acc[i][0] += a * w.x;
                acc[i][1] += a * w.y;
                acc[i][2] += a * w.z;
                acc[i][3] += a * w.w;
            }
        }
        __syncthreads();
    }

    int col = tx * 4;
    if (EPI == 0) {
        float4 b = *(const float4*)(ba + col);
#pragma unroll
        for (int i = 0; i < 8; i++) {
            int gr = row0 + ty * 8 + i;
            if (gr < M) {
                float4 o;
                o.x = fmaxf(acc[i][0] + b.x, 0.f);
                o.y = fmaxf(acc[i][1] + b.y, 0.f);
                o.z = fmaxf(acc[i][2] + b.z, 0.f);
                o.w = fmaxf(acc[i][3] + b.w, 0.f);
                *(float4*)(C + (size_t)gr * FDIM + col) = o;
            }
        }
    } else {
        bool is_mu = (col < 64);
        int c2 = is_mu ? col : (col - 64);
        const float* bp = is_mu ? ba : bb;
        float4 b = *(const float4*)(bp + c2);
        size_t base = is_mu ? 0 : (size_t)M * 64;
#pragma unroll
        for (int i = 0; i < 8; i++) {
            int gr = row0 + ty * 8 + i;
            if (gr < M) {
                float4 o;
                o.x = acc[i][0] + b.x;
                o.y = acc[i][1] + b.y;
                o.z = acc[i][2] + b.z;
                o.w = acc[i][3] + b.w;
                *(float4*)(C + base + (size_t)gr * 64 + c2) = o;
            }
        }
    }
}

// ---------------------------------------------------------------------------
extern "C" void kernel_launch(void* const* d_in, const int* in_sizes, int n_in,
                              void* d_out, int out_size, void* d_ws, size_t ws_size,
                              hipStream_t stream) {
    const float* x    = (const float*)d_in[0];
    const int*   ei   = (const int*)d_in[1];
    const float* W1   = (const float*)d_in[2];
    const float* b1   = (const float*)d_in[3];
    const float* Wmu  = (const float*)d_in[4];
    const float* bmu  = (const float*)d_in[5];
    const float* Wlog = (const float*)d_in[6];
    const float* blog = (const float*)d_in[7];
    float* out = (float*)d_out;

    const int N = N_NODES;
    const int E = in_sizes[1] / 2;
    const int* src = ei;
    const int* dst = ei + E;

    auto align256 = [](size_t x) { return (x + 255) & ~(size_t)255; };
    char* ws = (char*)d_ws;
    size_t off = 0;
    int*   counts  = (int*)(ws + off);  off += align256((size_t)NPAD * 4);
    int*   cursor  = (int*)(ws + off);  off += align256((size_t)NPAD * 4);
    int*   offsets = (int*)(ws + off);  off += align256((size_t)NPAD * 4);
    int*   local   = (int*)(ws + off);  off += align256((size_t)NPAD * 4);
    int*   bsums   = (int*)(ws + off);  off += align256(256 * 4);
    int*   boffs   = (int*)(ws + off);  off += align256(256 * 4);
    float* dinv    = (float*)(ws + off); off += align256((size_t)N * 4);
    int2*  csr_ew  = (int2*)(ws + off); off += align256((size_t)E * 8);
    float* bufA    = (float*)(ws + off); off += align256((size_t)N * FDIM * 4);
    float* bufB    = (float*)(ws + off); off += align256((size_t)N * FDIM * 4);

    // 1. build CSR + dinv
    hipMemsetAsync(counts, 0, (size_t)NPAD * 4, stream);
    count_kernel<<<(E + 255) / 256, 256, 0, stream>>>(dst, counts, E);
    dinv_kernel<<<(N + 255) / 256, 256, 0, stream>>>(counts, dinv, N);
    scan_local_kernel<<<SCAN_NB, 256, 0, stream>>>(counts, local, bsums);
    scan_bsums_kernel<<<1, 64, 0, stream>>>(bsums, boffs, SCAN_NB);
    scan_add_kernel<<<SCAN_NB, 256, 0, stream>>>(local, boffs, offsets, cursor);
    scatter_kernel<<<(E + 255) / 256, 256, 0, stream>>>(src, dst, dinv, cursor,
                                                        csr_ew, E);

    // 2. ax = A @ x   (half-wave per node: 8 nodes per 256-thread block)
    int agg_blocks = (N + 7) / 8;
    agg_kernel<<<agg_blocks, 256, 0, stream>>>(x, offsets, csr_ew, dinv, bufA, N);

    // 3. h1 = relu(ax @ W1 + b1)
    gemm128<0><<<(N + 63) / 64, 256, 0, stream>>>(bufA, W1, nullptr, b1, nullptr, bufB, N);

    // 4. ah = A @ h1
    agg_kernel<<<agg_blocks, 256, 0, stream>>>(bufB, offsets, csr_ew, dinv, bufA, N);

    // 5. [mu | logstd] -> d_out
    gemm128<1><<<(N + 63) / 64, 256, 0, stream>>>(bufA, Wmu, Wlog, bmu, blog, out, N);
}

// Round 5
// 244.224 us; speedup vs baseline: 1.5160x; 1.1241x over previous
//
#include <hip/hip_runtime.h>
#include <hip/hip_bf16.h>

#define N_NODES 50000
#define FDIM 128
#define NPAD 50176      // 49 * 1024, covers N_NODES+1
#define SCAN_NB 49

typedef short bf16x8 __attribute__((ext_vector_type(8)));
typedef float f32x4  __attribute__((ext_vector_type(4)));

__device__ __forceinline__ unsigned short rne_bf16(float f) {
    unsigned int u = __float_as_uint(f);
    unsigned int r = (u + 0x7FFFu + ((u >> 16) & 1u)) >> 16;
    return (unsigned short)r;
}
__device__ __forceinline__ float bf16_to_f32(unsigned short s) {
    return __uint_as_float(((unsigned int)s) << 16);
}
__device__ __forceinline__ void split_bf16(float f, unsigned short& h, unsigned short& l) {
    h = rne_bf16(f);
    l = rne_bf16(f - bf16_to_f32(h));
}
// unpack one dword holding 2 bf16 (elem0 = low 16)
__device__ __forceinline__ void unpack2(unsigned int d, float& f0, float& f1) {
    f0 = __uint_as_float(d << 16);
    f1 = __uint_as_float(d & 0xFFFF0000u);
}
// acc[0..7] += wt * row(m)  (8 bf16 in a uint4)
__device__ __forceinline__ void acc_row(const uint4& m, float wt, float* a) {
    float f0, f1;
    unpack2(m.x, f0, f1); a[0] += wt * f0; a[1] += wt * f1;
    unpack2(m.y, f0, f1); a[2] += wt * f0; a[3] += wt * f1;
    unpack2(m.z, f0, f1); a[4] += wt * f0; a[5] += wt * f1;
    unpack2(m.w, f0, f1); a[6] += wt * f0; a[7] += wt * f1;
}

// ---------------------------------------------------------------------------
// CSR build
// ---------------------------------------------------------------------------
__global__ __launch_bounds__(256) void count_kernel(const int* __restrict__ dst,
                                                    int* __restrict__ counts, int E) {
    int e = blockIdx.x * blockDim.x + threadIdx.x;
    if (e < E) atomicAdd(&counts[dst[e]], 1);
}

__global__ __launch_bounds__(256) void dinv_kernel(const int* __restrict__ counts,
                                                   float* __restrict__ dinv, int n) {
    int v = blockIdx.x * blockDim.x + threadIdx.x;
    if (v < n) dinv[v] = rsqrtf((float)counts[v] + 1.0f);
}

__global__ __launch_bounds__(256) void scan_local_kernel(const int* __restrict__ counts,
                                                         int* __restrict__ local,
                                                         int* __restrict__ bsums) {
    int t    = threadIdx.x;
    int lane = t & 63;
    int wid  = t >> 6;
    int base = blockIdx.x * 1024 + t * 4;
    int4 v = *(const int4*)(counts + base);
    int s = v.x + v.y + v.z + v.w;
    int incl = s;
#pragma unroll
    for (int off = 1; off < 64; off <<= 1) {
        int u = __shfl_up(incl, off, 64);
        if (lane >= off) incl += u;
    }
    __shared__ int wtot[4];
    if (lane == 63) wtot[wid] = incl;
    __syncthreads();
    int wbase = 0;
#pragma unroll
    for (int w = 0; w < 3; w++) wbase += (w < wid) ? wtot[w] : 0;
    int excl = wbase + incl - s;
    int4 o;
    o.x = excl;
    o.y = excl + v.x;
    o.z = o.y + v.y;
    o.w = o.z + v.z;
    *(int4*)(local + base) = o;
    if (t == 255) bsums[blockIdx.x] = wbase + incl;
}

__global__ __launch_bounds__(64) void scan_bsums_kernel(const int* __restrict__ bsums,
                                                        int* __restrict__ boffs, int nb) {
    int lane = threadIdx.x;
    int v = (lane < nb) ? bsums[lane] : 0;
    int incl = v;
#pragma unroll
    for (int off = 1; off < 64; off <<= 1) {
        int u = __shfl_up(incl, off, 64);
        if (lane >= off) incl += u;
    }
    if (lane < nb) boffs[lane] = incl - v;
}

__global__ __launch_bounds__(256) void scan_add_kernel(const int* __restrict__ local,
                                                       const int* __restrict__ boffs,
                                                       int* __restrict__ offsets,
                                                       int* __restrict__ cursor) {
    int base = blockIdx.x * 1024 + threadIdx.x * 4;
    int bo = boffs[blockIdx.x];
    int4 v = *(const int4*)(local + base);
    v.x += bo; v.y += bo; v.z += bo; v.w += bo;
    *(int4*)(offsets + base) = v;
    *(int4*)(cursor + base)  = v;
}

__global__ __launch_bounds__(256) void scatter_kernel(const int* __restrict__ src,
                                                      const int* __restrict__ dst,
                                                      const float* __restrict__ dinv,
                                                      int* __restrict__ cursor,
                                                      int2* __restrict__ csr_ew, int E) {
    int e = blockIdx.x * blockDim.x + threadIdx.x;
    if (e < E) {
        int s = src[e], d = dst[e];
        float w = dinv[s] * dinv[d];
        int pos = atomicAdd(&cursor[d], 1);
        csr_ew[pos] = make_int2(s, __float_as_int(w));
    }
}

// ---------------------------------------------------------------------------
// Prep: x fp32 -> bf16; W1 / [Wmu|Wlog] -> transposed bf16 hi/lo splits
// ---------------------------------------------------------------------------
__global__ __launch_bounds__(256) void cvt_x_kernel(const float* __restrict__ x,
                                                    unsigned short* __restrict__ xb, int n4) {
    int i = blockIdx.x * blockDim.x + threadIdx.x;
    if (i >= n4) return;
    float4 v = ((const float4*)x)[i];
    unsigned int d0 = (unsigned int)rne_bf16(v.x) | ((unsigned int)rne_bf16(v.y) << 16);
    unsigned int d1 = (unsigned int)rne_bf16(v.z) | ((unsigned int)rne_bf16(v.w) << 16);
    ((uint2*)xb)[i] = make_uint2(d0, d1);
}

__global__ __launch_bounds__(256) void cvt_w_kernel(const float* __restrict__ W1,
                                                    const float* __restrict__ Wmu,
                                                    const float* __restrict__ Wlog,
                                                    unsigned short* __restrict__ W1thi,
                                                    unsigned short* __restrict__ W1tlo,
                                                    unsigned short* __restrict__ Wcthi,
                                                    unsigned short* __restrict__ Wctlo) {
    int tid = blockIdx.x * 256 + threadIdx.x;   // 0..16383
    int n = tid & 127, k = tid >> 7;
    unsigned short h, l;
    float v1 = W1[k * 128 + n];
    split_bf16(v1, h, l);
    W1thi[n * 128 + k] = h;
    W1tlo[n * 128 + k] = l;
    float v2 = (n < 64) ? Wmu[k * 64 + n] : Wlog[k * 64 + (n - 64)];
    split_bf16(v2, h, l);
    Wcthi[n * 128 + k] = h;
    Wctlo[n * 128 + k] = l;
}

// ---------------------------------------------------------------------------
// Aggregation on bf16 rows (256B), quarter-wave (16 lanes x 16B) per node,
// 4 nodes/wave, unroll 4 -> 16 row-gathers in flight per wave.
// Output: bf16 hi/lo split (feeds MFMA GEMM).
// ---------------------------------------------------------------------------
__global__ __launch_bounds__(256) void agg_bf16_kernel(const unsigned short* __restrict__ X,
                                                       const int* __restrict__ offsets,
                                                       const int2* __restrict__ csr_ew,
                                                       const float* __restrict__ dinv,
                                                       unsigned short* __restrict__ Yhi,
                                                       unsigned short* __restrict__ Ylo,
                                                       int n) {
    int node = (blockIdx.x << 4) + (threadIdx.x >> 4);
    int l16  = threadIdx.x & 15;
    if (node >= n) return;
    const uint4* X16 = (const uint4*)X;   // row = 16 uint4 (128 bf16)

    float dv = dinv[node];
    float sw = dv * dv;
    float a[8];
    {
        uint4 xv = X16[(size_t)node * 16 + l16];
        float f0, f1;
        unpack2(xv.x, f0, f1); a[0] = sw * f0; a[1] = sw * f1;
        unpack2(xv.y, f0, f1); a[2] = sw * f0; a[3] = sw * f1;
        unpack2(xv.z, f0, f1); a[4] = sw * f0; a[5] = sw * f1;
        unpack2(xv.w, f0, f1); a[6] = sw * f0; a[7] = sw * f1;
    }

    int beg = offsets[node], end = offsets[node + 1];
    int i = beg;
    for (; i + 4 <= end; i += 4) {
        int2 e0 = csr_ew[i];
        int2 e1 = csr_ew[i + 1];
        int2 e2 = csr_ew[i + 2];
        int2 e3 = csr_ew[i + 3];
        uint4 m0 = X16[(size_t)e0.x * 16 + l16];
        uint4 m1 = X16[(size_t)e1.x * 16 + l16];
        uint4 m2 = X16[(size_t)e2.x * 16 + l16];
        uint4 m3 = X16[(size_t)e3.x * 16 + l16];
        acc_row(m0, __int_as_float(e0.y), a);
        acc_row(m1, __int_as_float(e1.y), a);
        acc_row(m2, __int_as_float(e2.y), a);
        acc_row(m3, __int_as_float(e3.y), a);
    }
    for (; i < end; i++) {
        int2 e = csr_ew[i];
        uint4 m = X16[(size_t)e.x * 16 + l16];
        acc_row(m, __int_as_float(e.y), a);
    }

    unsigned short h[8], l[8];
#pragma unroll
    for (int j = 0; j < 8; j++) split_bf16(a[j], h[j], l[j]);
    uint4 ph, pl;
    ph.x = (unsigned int)h[0] | ((unsigned int)h[1] << 16);
    ph.y = (unsigned int)h[2] | ((unsigned int)h[3] << 16);
    ph.z = (unsigned int)h[4] | ((unsigned int)h[5] << 16);
    ph.w = (unsigned int)h[6] | ((unsigned int)h[7] << 16);
    pl.x = (unsigned int)l[0] | ((unsigned int)l[1] << 16);
    pl.y = (unsigned int)l[2] | ((unsigned int)l[3] << 16);
    pl.z = (unsigned int)l[4] | ((unsigned int)l[5] << 16);
    pl.w = (unsigned int)l[6] | ((unsigned int)l[7] << 16);
    ((uint4*)Yhi)[(size_t)node * 16 + l16] = ph;
    ((uint4*)Ylo)[(size_t)node * 16 + l16] = pl;
}

// ---------------------------------------------------------------------------
// MFMA GEMM: D[M,128] = (Ahi+Alo)[M,128] @ W[128,128], W pre-split/transposed.
// 3-product split: D = Ah*Wh + Ah*Wl + Al*Wh (fp32 accumulate).
// Wave = 16 rows x 128 cols; block = 4 waves = 64 rows. No LDS.
// EPI 0: h = bf16(relu(D + b1)) -> H
// EPI 1: cols<64 -> out[row*64+c]+bmu ; cols>=64 -> out[N*64+row*64+c-64]+blog
// ---------------------------------------------------------------------------
template <int EPI>
__global__ __launch_bounds__(256) void mfma_gemm_kernel(const unsigned short* __restrict__ Ahi,
                                                        const unsigned short* __restrict__ Alo,
                                                        const unsigned short* __restrict__ Wthi,
                                                        const unsigned short* __restrict__ Wtlo,
                                                        const float* __restrict__ ba,
                                                        const float* __restrict__ bb,
                                                        unsigned short* __restrict__ H,
                                                        float* __restrict__ out, int M) {
    int wave = threadIdx.x >> 6;
    int lane = threadIdx.x & 63;
    int m16  = lane & 15;       // A row within tile / D col within tile
    int kg   = lane >> 4;       // 0..3
    int rbase = blockIdx.x * 64 + wave * 16;
    int arow  = rbase + m16;
    bool rok  = arow < M;

    const unsigned short* arh = Ahi + (size_t)(rok ? arow : 0) * 128;
    const unsigned short* arl = Alo + (size_t)(rok ? arow : 0) * 128;
    bf16x8 ah[4], al[4];
#pragma unroll
    for (int kt = 0; kt < 4; kt++) {
        bf16x8 vh = *(const bf16x8*)(const void*)(arh + kt * 32 + kg * 8);
        bf16x8 vl = *(const bf16x8*)(const void*)(arl + kt * 32 + kg * 8);
        ah[kt] = rok ? vh : (bf16x8)(short)0;
        al[kt] = rok ? vl : (bf16x8)(short)0;
    }

    f32x4 acc[8];
#pragma unroll
    for (int nt = 0; nt < 8; nt++) {
        f32x4 a = {0.f, 0.f, 0.f, 0.f};
        const unsigned short* wrh = Wthi + (size_t)(nt * 16 + m16) * 128;
        const unsigned short* wrl = Wtlo + (size_t)(nt * 16 + m16) * 128;
#pragma unroll
        for (int kt = 0; kt < 4; kt++) {
            bf16x8 bh = *(const bf16x8*)(const void*)(wrh + kt * 32 + kg * 8);
            bf16x8 bl = *(const bf16x8*)(const void*)(wrl + kt * 32 + kg * 8);
            a = __builtin_amdgcn_mfma_f32_16x16x32_bf16(ah[kt], bh, a, 0, 0, 0);
            a = __builtin_amdgcn_mfma_f32_16x16x32_bf16(ah[kt], bl, a, 0, 0, 0);
            a = __builtin_amdgcn_mfma_f32_16x16x32_bf16(al[kt], bh, a, 0, 0, 0);
        }
        acc[nt] = a;
    }

    // epilogue: D[row = rbase + kg*4 + j][col = nt*16 + m16]
#pragma unroll
    for (int nt = 0; nt < 8; nt++) {
        int n0 = nt * 16 + m16;
        if (EPI == 0) {
            float b = ba[n0];
#pragma unroll
            for (int j = 0; j < 4; j++) {
                int r = rbase + kg * 4 + j;
                if (r < M) {
                    float v = fmaxf(acc[nt][j] + b, 0.f);
                    H[(size_t)r * 128 + n0] = rne_bf16(v);
                }
            }
        } else {
            bool is_mu = (n0 < 64);
            int c = is_mu ? n0 : (n0 - 64);
            float b = is_mu ? ba[c] : bb[c];
            size_t base = is_mu ? 0 : (size_t)N_NODES * 64;
#pragma unroll
            for (int j = 0; j < 4; j++) {
                int r = rbase + kg * 4 + j;
                if (r < M) out[base + (size_t)r * 64 + c] = acc[nt][j] + b;
            }
        }
    }
}

// ---------------------------------------------------------------------------
extern "C" void kernel_launch(void* const* d_in, const int* in_sizes, int n_in,
                              void* d_out, int out_size, void* d_ws, size_t ws_size,
                              hipStream_t stream) {
    const float* x    = (const float*)d_in[0];
    const int*   ei   = (const int*)d_in[1];
    const float* W1   = (const float*)d_in[2];
    const float* b1   = (const float*)d_in[3];
    const float* Wmu  = (const float*)d_in[4];
    const float* bmu  = (const float*)d_in[5];
    const float* Wlog = (const float*)d_in[6];
    const float* blog = (const float*)d_in[7];
    float* out = (float*)d_out;

    const int N = N_NODES;
    const int E = in_sizes[1] / 2;
    const int* src = ei;
    const int* dst = ei + E;

    auto align256 = [](size_t v) { return (v + 255) & ~(size_t)255; };
    char* ws = (char*)d_ws;
    size_t off = 0;
    int*   counts  = (int*)(ws + off);  off += align256((size_t)NPAD * 4);
    int*   cursor  = (int*)(ws + off);  off += align256((size_t)NPAD * 4);
    int*   offsets = (int*)(ws + off);  off += align256((size_t)NPAD * 4);
    int*   local   = (int*)(ws + off);  off += align256((size_t)NPAD * 4);
    int*   bsums   = (int*)(ws + off);  off += align256(256 * 4);
    int*   boffs   = (int*)(ws + off);  off += align256(256 * 4);
    float* dinv    = (float*)(ws + off); off += align256((size_t)N * 4);
    int2*  csr_ew  = (int2*)(ws + off); off += align256((size_t)E * 8);
    unsigned short* xb    = (unsigned short*)(ws + off); off += align256((size_t)N * FDIM * 2);
    unsigned short* Hb    = (unsigned short*)(ws + off); off += align256((size_t)N * FDIM * 2);
    unsigned short* Aghi  = (unsigned short*)(ws + off); off += align256((size_t)N * FDIM * 2);
    unsigned short* Aglo  = (unsigned short*)(ws + off); off += align256((size_t)N * FDIM * 2);
    unsigned short* W1thi = (unsigned short*)(ws + off); off += align256(128 * 128 * 2);
    unsigned short* W1tlo = (unsigned short*)(ws + off); off += align256(128 * 128 * 2);
    unsigned short* Wcthi = (unsigned short*)(ws + off); off += align256(128 * 128 * 2);
    unsigned short* Wctlo = (unsigned short*)(ws + off); off += align256(128 * 128 * 2);

    // 1. CSR + dinv
    hipMemsetAsync(counts, 0, (size_t)NPAD * 4, stream);
    count_kernel<<<(E + 255) / 256, 256, 0, stream>>>(dst, counts, E);
    dinv_kernel<<<(N + 255) / 256, 256, 0, stream>>>(counts, dinv, N);
    scan_local_kernel<<<SCAN_NB, 256, 0, stream>>>(counts, local, bsums);
    scan_bsums_kernel<<<1, 64, 0, stream>>>(bsums, boffs, SCAN_NB);
    scan_add_kernel<<<SCAN_NB, 256, 0, stream>>>(local, boffs, offsets, cursor);
    scatter_kernel<<<(E + 255) / 256, 256, 0, stream>>>(src, dst, dinv, cursor, csr_ew, E);

    // 2. prep conversions
    cvt_x_kernel<<<(N * FDIM / 4 + 255) / 256, 256, 0, stream>>>(x, xb, N * FDIM / 4);
    cvt_w_kernel<<<64, 256, 0, stream>>>(W1, Wmu, Wlog, W1thi, W1tlo, Wcthi, Wctlo);

    // 3. agg1: (A x) -> hi/lo split
    agg_bf16_kernel<<<(N + 15) / 16, 256, 0, stream>>>(xb, offsets, csr_ew, dinv, Aghi, Aglo, N);

    // 4. h = bf16(relu((Ax) @ W1 + b1))
    mfma_gemm_kernel<0><<<(N + 63) / 64, 256, 0, stream>>>(Aghi, Aglo, W1thi, W1tlo,
                                                           b1, nullptr, Hb, nullptr, N);

    // 5. agg2: (A h) -> hi/lo split
    agg_bf16_kernel<<<(N + 15) / 16, 256, 0, stream>>>(Hb, offsets, csr_ew, dinv, Aghi, Aglo, N);

    // 6. [mu | logstd] = (Ah) @ [Wmu|Wlog] + bias -> d_out
    mfma_gemm_kernel<1><<<(N + 63) / 64, 256, 0, stream>>>(Aghi, Aglo, Wcthi, Wctlo,
                                                           bmu, blog, nullptr, out, N);
}

// Round 6
// 216.165 us; speedup vs baseline: 1.7128x; 1.1298x over previous
//
#include <hip/hip_runtime.h>
#include <hip/hip_bf16.h>

#define N_NODES 50000
#define FDIM 128
#define NPAD 50176      // 49 * 1024, covers N_NODES+1
#define SCAN_NB 49

typedef short bf16x8 __attribute__((ext_vector_type(8)));
typedef float f32x4  __attribute__((ext_vector_type(4)));

__device__ __forceinline__ unsigned short rne_bf16(float f) {
    unsigned int u = __float_as_uint(f);
    unsigned int r = (u + 0x7FFFu + ((u >> 16) & 1u)) >> 16;
    return (unsigned short)r;
}
__device__ __forceinline__ float bf16_to_f32(unsigned short s) {
    return __uint_as_float(((unsigned int)s) << 16);
}
__device__ __forceinline__ void split_bf16(float f, unsigned short& h, unsigned short& l) {
    h = rne_bf16(f);
    l = rne_bf16(f - bf16_to_f32(h));
}
// unpack one dword holding 2 bf16 (elem0 = low 16)
__device__ __forceinline__ void unpack2(unsigned int d, float& f0, float& f1) {
    f0 = __uint_as_float(d << 16);
    f1 = __uint_as_float(d & 0xFFFF0000u);
}
// acc[0..7] += wt * row(m)  (8 bf16 in a uint4)
__device__ __forceinline__ void acc_row(const uint4& m, float wt, float* a) {
    float f0, f1;
    unpack2(m.x, f0, f1); a[0] += wt * f0; a[1] += wt * f1;
    unpack2(m.y, f0, f1); a[2] += wt * f0; a[3] += wt * f1;
    unpack2(m.z, f0, f1); a[4] += wt * f0; a[5] += wt * f1;
    unpack2(m.w, f0, f1); a[6] += wt * f0; a[7] += wt * f1;
}

// ---------------------------------------------------------------------------
// CSR build: count in-degree AND capture each edge's rank within its dst
// ---------------------------------------------------------------------------
__global__ __launch_bounds__(256) void count_kernel(const int* __restrict__ dst,
                                                    int* __restrict__ counts,
                                                    int* __restrict__ rank, int E) {
    int e = blockIdx.x * blockDim.x + threadIdx.x;
    if (e < E) rank[e] = atomicAdd(&counts[dst[e]], 1);
}

__global__ __launch_bounds__(256) void dinv_kernel(const int* __restrict__ counts,
                                                   float* __restrict__ dinv, int n) {
    int v = blockIdx.x * blockDim.x + threadIdx.x;
    if (v < n) dinv[v] = rsqrtf((float)counts[v] + 1.0f);
}

__global__ __launch_bounds__(256) void scan_local_kernel(const int* __restrict__ counts,
                                                         int* __restrict__ local,
                                                         int* __restrict__ bsums) {
    int t    = threadIdx.x;
    int lane = t & 63;
    int wid  = t >> 6;
    int base = blockIdx.x * 1024 + t * 4;
    int4 v = *(const int4*)(counts + base);
    int s = v.x + v.y + v.z + v.w;
    int incl = s;
#pragma unroll
    for (int off = 1; off < 64; off <<= 1) {
        int u = __shfl_up(incl, off, 64);
        if (lane >= off) incl += u;
    }
    __shared__ int wtot[4];
    if (lane == 63) wtot[wid] = incl;
    __syncthreads();
    int wbase = 0;
#pragma unroll
    for (int w = 0; w < 3; w++) wbase += (w < wid) ? wtot[w] : 0;
    int excl = wbase + incl - s;
    int4 o;
    o.x = excl;
    o.y = excl + v.x;
    o.z = o.y + v.y;
    o.w = o.z + v.z;
    *(int4*)(local + base) = o;
    if (t == 255) bsums[blockIdx.x] = wbase + incl;
}

__global__ __launch_bounds__(64) void scan_bsums_kernel(const int* __restrict__ bsums,
                                                        int* __restrict__ boffs, int nb) {
    int lane = threadIdx.x;
    int v = (lane < nb) ? bsums[lane] : 0;
    int incl = v;
#pragma unroll
    for (int off = 1; off < 64; off <<= 1) {
        int u = __shfl_up(incl, off, 64);
        if (lane >= off) incl += u;
    }
    if (lane < nb) boffs[lane] = incl - v;
}

__global__ __launch_bounds__(256) void scan_add_kernel(const int* __restrict__ local,
                                                       const int* __restrict__ boffs,
                                                       int* __restrict__ offsets) {
    int base = blockIdx.x * 1024 + threadIdx.x * 4;
    int bo = boffs[blockIdx.x];
    int4 v = *(const int4*)(local + base);
    v.x += bo; v.y += bo; v.z += bo; v.w += bo;
    *(int4*)(offsets + base) = v;
}

// atomic-free scatter: pos = offsets[dst] + rank  (4B payload per edge)
__global__ __launch_bounds__(256) void scatter_kernel(const int* __restrict__ src,
                                                      const int* __restrict__ dst,
                                                      const int* __restrict__ rank,
                                                      const int* __restrict__ offsets,
                                                      int* __restrict__ csr_src, int E) {
    int e = blockIdx.x * blockDim.x + threadIdx.x;
    if (e < E) {
        int d = dst[e];
        int pos = offsets[d] + rank[e];
        csr_src[pos] = src[e];
    }
}

// ---------------------------------------------------------------------------
// Prep: x fp32 -> bf16; W1 / [Wmu|Wlog] -> transposed bf16 hi/lo splits
// ---------------------------------------------------------------------------
__global__ __launch_bounds__(256) void cvt_x_kernel(const float* __restrict__ x,
                                                    unsigned short* __restrict__ xb, int n4) {
    int i = blockIdx.x * blockDim.x + threadIdx.x;
    if (i >= n4) return;
    float4 v = ((const float4*)x)[i];
    unsigned int d0 = (unsigned int)rne_bf16(v.x) | ((unsigned int)rne_bf16(v.y) << 16);
    unsigned int d1 = (unsigned int)rne_bf16(v.z) | ((unsigned int)rne_bf16(v.w) << 16);
    ((uint2*)xb)[i] = make_uint2(d0, d1);
}

__global__ __launch_bounds__(256) void cvt_w_kernel(const float* __restrict__ W1,
                                                    const float* __restrict__ Wmu,
                                                    const float* __restrict__ Wlog,
                                                    unsigned short* __restrict__ W1thi,
                                                    unsigned short* __restrict__ W1tlo,
                                                    unsigned short* __restrict__ Wcthi,
                                                    unsigned short* __restrict__ Wctlo) {
    int tid = blockIdx.x * 256 + threadIdx.x;   // 0..16383
    int n = tid & 127, k = tid >> 7;
    unsigned short h, l;
    float v1 = W1[k * 128 + n];
    split_bf16(v1, h, l);
    W1thi[n * 128 + k] = h;
    W1tlo[n * 128 + k] = l;
    float v2 = (n < 64) ? Wmu[k * 64 + n] : Wlog[k * 64 + (n - 64)];
    split_bf16(v2, h, l);
    Wcthi[n * 128 + k] = h;
    Wctlo[n * 128 + k] = l;
}

// ---------------------------------------------------------------------------
// Aggregation on bf16 rows (256B), quarter-wave (16 lanes x 16B) per node,
// 4 nodes/wave, unroll 4 -> 16 row-gathers in flight per wave.
// Weight recomputed on the fly: w = dinv[node] * dinv[src].
// Output: bf16 hi/lo split (feeds MFMA GEMM).
// ---------------------------------------------------------------------------
__global__ __launch_bounds__(256) void agg_bf16_kernel(const unsigned short* __restrict__ X,
                                                       const int* __restrict__ offsets,
                                                       const int* __restrict__ csr_src,
                                                       const float* __restrict__ dinv,
                                                       unsigned short* __restrict__ Yhi,
                                                       unsigned short* __restrict__ Ylo,
                                                       int n) {
    int node = (blockIdx.x << 4) + (threadIdx.x >> 4);
    int l16  = threadIdx.x & 15;
    if (node >= n) return;
    const uint4* X16 = (const uint4*)X;   // row = 16 uint4 (128 bf16)

    float dv = dinv[node];
    float sw = dv * dv;
    float a[8];
    {
        uint4 xv = X16[(size_t)node * 16 + l16];
        float f0, f1;
        unpack2(xv.x, f0, f1); a[0] = sw * f0; a[1] = sw * f1;
        unpack2(xv.y, f0, f1); a[2] = sw * f0; a[3] = sw * f1;
        unpack2(xv.z, f0, f1); a[4] = sw * f0; a[5] = sw * f1;
        unpack2(xv.w, f0, f1); a[6] = sw * f0; a[7] = sw * f1;
    }

    int beg = offsets[node], end = offsets[node + 1];
    int i = beg;
    for (; i + 4 <= end; i += 4) {
        int s0 = csr_src[i];
        int s1 = csr_src[i + 1];
        int s2 = csr_src[i + 2];
        int s3 = csr_src[i + 3];
        uint4 m0 = X16[(size_t)s0 * 16 + l16];
        uint4 m1 = X16[(size_t)s1 * 16 + l16];
        uint4 m2 = X16[(size_t)s2 * 16 + l16];
        uint4 m3 = X16[(size_t)s3 * 16 + l16];
        float w0 = dv * dinv[s0];
        float w1 = dv * dinv[s1];
        float w2 = dv * dinv[s2];
        float w3 = dv * dinv[s3];
        acc_row(m0, w0, a);
        acc_row(m1, w1, a);
        acc_row(m2, w2, a);
        acc_row(m3, w3, a);
    }
    for (; i < end; i++) {
        int s = csr_src[i];
        uint4 m = X16[(size_t)s * 16 + l16];
        acc_row(m, dv * dinv[s], a);
    }

    unsigned short h[8], l[8];
#pragma unroll
    for (int j = 0; j < 8; j++) split_bf16(a[j], h[j], l[j]);
    uint4 ph, pl;
    ph.x = (unsigned int)h[0] | ((unsigned int)h[1] << 16);
    ph.y = (unsigned int)h[2] | ((unsigned int)h[3] << 16);
    ph.z = (unsigned int)h[4] | ((unsigned int)h[5] << 16);
    ph.w = (unsigned int)h[6] | ((unsigned int)h[7] << 16);
    pl.x = (unsigned int)l[0] | ((unsigned int)l[1] << 16);
    pl.y = (unsigned int)l[2] | ((unsigned int)l[3] << 16);
    pl.z = (unsigned int)l[4] | ((unsigned int)l[5] << 16);
    pl.w = (unsigned int)l[6] | ((unsigned int)l[7] << 16);
    ((uint4*)Yhi)[(size_t)node * 16 + l16] = ph;
    ((uint4*)Ylo)[(size_t)node * 16 + l16] = pl;
}

// ---------------------------------------------------------------------------
// MFMA GEMM: D[M,128] = (Ahi+Alo)[M,128] @ W[128,128], W pre-split/transposed.
// 3-product split: D = Ah*Wh + Ah*Wl + Al*Wh (fp32 accumulate).
// Wave = 16 rows x 128 cols; block = 4 waves = 64 rows. No LDS.
// EPI 0: h = bf16(relu(D + b1)) -> H
// EPI 1: cols<64 -> out[row*64+c]+bmu ; cols>=64 -> out[N*64+row*64+c-64]+blog
// ---------------------------------------------------------------------------
template <int EPI>
__global__ __launch_bounds__(256) void mfma_gemm_kernel(const unsigned short* __restrict__ Ahi,
                                                        const unsigned short* __restrict__ Alo,
                                                        const unsigned short* __restrict__ Wthi,
                                                        const unsigned short* __restrict__ Wtlo,
                                                        const float* __restrict__ ba,
                                                        const float* __restrict__ bb,
                                                        unsigned short* __restrict__ H,
                                                        float* __restrict__ out, int M) {
    int wave = threadIdx.x >> 6;
    int lane = threadIdx.x & 63;
    int m16  = lane & 15;       // A row within tile / D col within tile
    int kg   = lane >> 4;       // 0..3
    int rbase = blockIdx.x * 64 + wave * 16;
    int arow  = rbase + m16;
    bool rok  = arow < M;

    const unsigned short* arh = Ahi + (size_t)(rok ? arow : 0) * 128;
    const unsigned short* arl = Alo + (size_t)(rok ? arow : 0) * 128;
    bf16x8 ah[4], al[4];
#pragma unroll
    for (int kt = 0; kt < 4; kt++) {
        bf16x8 vh = *(const bf16x8*)(const void*)(arh + kt * 32 + kg * 8);
        bf16x8 vl = *(const bf16x8*)(const void*)(arl + kt * 32 + kg * 8);
        ah[kt] = rok ? vh : (bf16x8)(short)0;
        al[kt] = rok ? vl : (bf16x8)(short)0;
    }

    f32x4 acc[8];
#pragma unroll
    for (int nt = 0; nt < 8; nt++) {
        f32x4 a = {0.f, 0.f, 0.f, 0.f};
        const unsigned short* wrh = Wthi + (size_t)(nt * 16 + m16) * 128;
        const unsigned short* wrl = Wtlo + (size_t)(nt * 16 + m16) * 128;
#pragma unroll
        for (int kt = 0; kt < 4; kt++) {
            bf16x8 bh = *(const bf16x8*)(const void*)(wrh + kt * 32 + kg * 8);
            bf16x8 bl = *(const bf16x8*)(const void*)(wrl + kt * 32 + kg * 8);
            a = __builtin_amdgcn_mfma_f32_16x16x32_bf16(ah[kt], bh, a, 0, 0, 0);
            a = __builtin_amdgcn_mfma_f32_16x16x32_bf16(ah[kt], bl, a, 0, 0, 0);
            a = __builtin_amdgcn_mfma_f32_16x16x32_bf16(al[kt], bh, a, 0, 0, 0);
        }
        acc[nt] = a;
    }

    // epilogue: D[row = rbase + kg*4 + j][col = nt*16 + m16]
#pragma unroll
    for (int nt = 0; nt < 8; nt++) {
        int n0 = nt * 16 + m16;
        if (EPI == 0) {
            float b = ba[n0];
#pragma unroll
            for (int j = 0; j < 4; j++) {
                int r = rbase + kg * 4 + j;
                if (r < M) {
                    float v = fmaxf(acc[nt][j] + b, 0.f);
                    H[(size_t)r * 128 + n0] = rne_bf16(v);
                }
            }
        } else {
            bool is_mu = (n0 < 64);
            int c = is_mu ? n0 : (n0 - 64);
            float b = is_mu ? ba[c] : bb[c];
            size_t base = is_mu ? 0 : (size_t)N_NODES * 64;
#pragma unroll
            for (int j = 0; j < 4; j++) {
                int r = rbase + kg * 4 + j;
                if (r < M) out[base + (size_t)r * 64 + c] = acc[nt][j] + b;
            }
        }
    }
}

// ---------------------------------------------------------------------------
extern "C" void kernel_launch(void* const* d_in, const int* in_sizes, int n_in,
                              void* d_out, int out_size, void* d_ws, size_t ws_size,
                              hipStream_t stream) {
    const float* x    = (const float*)d_in[0];
    const int*   ei   = (const int*)d_in[1];
    const float* W1   = (const float*)d_in[2];
    const float* b1   = (const float*)d_in[3];
    const float* Wmu  = (const float*)d_in[4];
    const float* bmu  = (const float*)d_in[5];
    const float* Wlog = (const float*)d_in[6];
    const float* blog = (const float*)d_in[7];
    float* out = (float*)d_out;

    const int N = N_NODES;
    const int E = in_sizes[1] / 2;
    const int* src = ei;
    const int* dst = ei + E;

    auto align256 = [](size_t v) { return (v + 255) & ~(size_t)255; };
    char* ws = (char*)d_ws;
    size_t off = 0;
    int*   counts  = (int*)(ws + off);  off += align256((size_t)NPAD * 4);
    int*   offsets = (int*)(ws + off);  off += align256((size_t)NPAD * 4);
    int*   local   = (int*)(ws + off);  off += align256((size_t)NPAD * 4);
    int*   bsums   = (int*)(ws + off);  off += align256(256 * 4);
    int*   boffs   = (int*)(ws + off);  off += align256(256 * 4);
    float* dinv    = (float*)(ws + off); off += align256((size_t)N * 4);
    int*   rank    = (int*)(ws + off);  off += align256((size_t)E * 4);
    int*   csr_src = (int*)(ws + off);  off += align256((size_t)E * 4);
    unsigned short* xb    = (unsigned short*)(ws + off); off += align256((size_t)N * FDIM * 2);
    unsigned short* Hb    = (unsigned short*)(ws + off); off += align256((size_t)N * FDIM * 2);
    unsigned short* Aghi  = (unsigned short*)(ws + off); off += align256((size_t)N * FDIM * 2);
    unsigned short* Aglo  = (unsigned short*)(ws + off); off += align256((size_t)N * FDIM * 2);
    unsigned short* W1thi = (unsigned short*)(ws + off); off += align256(128 * 128 * 2);
    unsigned short* W1tlo = (unsigned short*)(ws + off); off += align256(128 * 128 * 2);
    unsigned short* Wcthi = (unsigned short*)(ws + off); off += align256(128 * 128 * 2);
    unsigned short* Wctlo = (unsigned short*)(ws + off); off += align256(128 * 128 * 2);

    // 1. CSR + dinv (rank captured during count; scatter is atomic-free)
    hipMemsetAsync(counts, 0, (size_t)NPAD * 4, stream);
    count_kernel<<<(E + 255) / 256, 256, 0, stream>>>(dst, counts, rank, E);
    dinv_kernel<<<(N + 255) / 256, 256, 0, stream>>>(counts, dinv, N);
    scan_local_kernel<<<SCAN_NB, 256, 0, stream>>>(counts, local, bsums);
    scan_bsums_kernel<<<1, 64, 0, stream>>>(bsums, boffs, SCAN_NB);
    scan_add_kernel<<<SCAN_NB, 256, 0, stream>>>(local, boffs, offsets);
    scatter_kernel<<<(E + 255) / 256, 256, 0, stream>>>(src, dst, rank, offsets, csr_src, E);

    // 2. prep conversions
    cvt_x_kernel<<<(N * FDIM / 4 + 255) / 256, 256, 0, stream>>>(x, xb, N * FDIM / 4);
    cvt_w_kernel<<<64, 256, 0, stream>>>(W1, Wmu, Wlog, W1thi, W1tlo, Wcthi, Wctlo);

    // 3. agg1: (A x) -> hi/lo split
    agg_bf16_kernel<<<(N + 15) / 16, 256, 0, stream>>>(xb, offsets, csr_src, dinv, Aghi, Aglo, N);

    // 4. h = bf16(relu((Ax) @ W1 + b1))
    mfma_gemm_kernel<0><<<(N + 63) / 64, 256, 0, stream>>>(Aghi, Aglo, W1thi, W1tlo,
                                                           b1, nullptr, Hb, nullptr, N);

    // 5. agg2: (A h) -> hi/lo split
    agg_bf16_kernel<<<(N + 15) / 16, 256, 0, stream>>>(Hb, offsets, csr_src, dinv, Aghi, Aglo, N);

    // 6. [mu | logstd] = (Ah) @ [Wmu|Wlog] + bias -> d_out
    mfma_gemm_kernel<1><<<(N + 63) / 64, 256, 0, stream>>>(Aghi, Aglo, Wcthi, Wctlo,
                                                           bmu, blog, nullptr, out, N);
}

// Round 7
// 200.955 us; speedup vs baseline: 1.8425x; 1.0757x over previous
//
#include <hip/hip_runtime.h>
#include <hip/hip_bf16.h>

#define N_NODES 50000
#define FDIM 128
#define NPAD 50176      // 49 * 1024, covers N_NODES+1
#define SCAN_NB 49

typedef short bf16x8 __attribute__((ext_vector_type(8)));
typedef float f32x4  __attribute__((ext_vector_type(4)));

__device__ __forceinline__ unsigned short rne_bf16(float f) {
    unsigned int u = __float_as_uint(f);
    unsigned int r = (u + 0x7FFFu + ((u >> 16) & 1u)) >> 16;
    return (unsigned short)r;
}
__device__ __forceinline__ float bf16_to_f32(unsigned short s) {
    return __uint_as_float(((unsigned int)s) << 16);
}
__device__ __forceinline__ void split_bf16(float f, unsigned short& h, unsigned short& l) {
    h = rne_bf16(f);
    l = rne_bf16(f - bf16_to_f32(h));
}
// unpack one dword holding 2 bf16 (elem0 = low 16)
__device__ __forceinline__ void unpack2(unsigned int d, float& f0, float& f1) {
    f0 = __uint_as_float(d << 16);
    f1 = __uint_as_float(d & 0xFFFF0000u);
}
// acc[0..7] += wt * row(m)  (8 bf16 in a uint4)
__device__ __forceinline__ void acc_row(const uint4& m, float wt, float* a) {
    float f0, f1;
    unpack2(m.x, f0, f1); a[0] += wt * f0; a[1] += wt * f1;
    unpack2(m.y, f0, f1); a[2] += wt * f0; a[3] += wt * f1;
    unpack2(m.z, f0, f1); a[4] += wt * f0; a[5] += wt * f1;
    unpack2(m.w, f0, f1); a[6] += wt * f0; a[7] += wt * f1;
}

// ---------------------------------------------------------------------------
// zero counts (replaces rocclr fill dispatch in the graph)
// ---------------------------------------------------------------------------
__global__ __launch_bounds__(256) void zero_kernel(int4* __restrict__ p, int n4) {
    int i = blockIdx.x * 256 + threadIdx.x;
    if (i < n4) p[i] = make_int4(0, 0, 0, 0);
}

// ---------------------------------------------------------------------------
// CSR build: count in-degree AND capture each edge's rank within its dst
// ---------------------------------------------------------------------------
__global__ __launch_bounds__(256) void count_kernel(const int* __restrict__ dst,
                                                    int* __restrict__ counts,
                                                    int* __restrict__ rank, int E) {
    int e = blockIdx.x * blockDim.x + threadIdx.x;
    if (e < E) rank[e] = atomicAdd(&counts[dst[e]], 1);
}

__global__ __launch_bounds__(256) void dinv_kernel(const int* __restrict__ counts,
                                                   float* __restrict__ dinv, int n) {
    int v = blockIdx.x * blockDim.x + threadIdx.x;
    if (v < n) dinv[v] = rsqrtf((float)counts[v] + 1.0f);
}

__global__ __launch_bounds__(256) void scan_local_kernel(const int* __restrict__ counts,
                                                         int* __restrict__ local,
                                                         int* __restrict__ bsums) {
    int t    = threadIdx.x;
    int lane = t & 63;
    int wid  = t >> 6;
    int base = blockIdx.x * 1024 + t * 4;
    int4 v = *(const int4*)(counts + base);
    int s = v.x + v.y + v.z + v.w;
    int incl = s;
#pragma unroll
    for (int off = 1; off < 64; off <<= 1) {
        int u = __shfl_up(incl, off, 64);
        if (lane >= off) incl += u;
    }
    __shared__ int wtot[4];
    if (lane == 63) wtot[wid] = incl;
    __syncthreads();
    int wbase = 0;
#pragma unroll
    for (int w = 0; w < 3; w++) wbase += (w < wid) ? wtot[w] : 0;
    int excl = wbase + incl - s;
    int4 o;
    o.x = excl;
    o.y = excl + v.x;
    o.z = o.y + v.y;
    o.w = o.z + v.z;
    *(int4*)(local + base) = o;
    if (t == 255) bsums[blockIdx.x] = wbase + incl;
}

__global__ __launch_bounds__(64) void scan_bsums_kernel(const int* __restrict__ bsums,
                                                        int* __restrict__ boffs, int nb) {
    int lane = threadIdx.x;
    int v = (lane < nb) ? bsums[lane] : 0;
    int incl = v;
#pragma unroll
    for (int off = 1; off < 64; off <<= 1) {
        int u = __shfl_up(incl, off, 64);
        if (lane >= off) incl += u;
    }
    if (lane < nb) boffs[lane] = incl - v;
}

__global__ __launch_bounds__(256) void scan_add_kernel(const int* __restrict__ local,
                                                       const int* __restrict__ boffs,
                                                       int* __restrict__ offsets) {
    int base = blockIdx.x * 1024 + threadIdx.x * 4;
    int bo = boffs[blockIdx.x];
    int4 v = *(const int4*)(local + base);
    v.x += bo; v.y += bo; v.z += bo; v.w += bo;
    *(int4*)(offsets + base) = v;
}

// atomic-free scatter: pos = offsets[dst] + rank  (4B payload per edge)
__global__ __launch_bounds__(256) void scatter_kernel(const int* __restrict__ src,
                                                      const int* __restrict__ dst,
                                                      const int* __restrict__ rank,
                                                      const int* __restrict__ offsets,
                                                      int* __restrict__ csr_src, int E) {
    int e = blockIdx.x * blockDim.x + threadIdx.x;
    if (e < E) {
        int d = dst[e];
        int pos = offsets[d] + rank[e];
        csr_src[pos] = src[e];
    }
}

// ---------------------------------------------------------------------------
// Prep: x fp32 -> bf16; W1 / [Wmu|Wlog] -> transposed bf16 hi/lo splits
// ---------------------------------------------------------------------------
__global__ __launch_bounds__(256) void cvt_x_kernel(const float* __restrict__ x,
                                                    unsigned short* __restrict__ xb, int n4) {
    int i = blockIdx.x * blockDim.x + threadIdx.x;
    if (i >= n4) return;
    float4 v = ((const float4*)x)[i];
    unsigned int d0 = (unsigned int)rne_bf16(v.x) | ((unsigned int)rne_bf16(v.y) << 16);
    unsigned int d1 = (unsigned int)rne_bf16(v.z) | ((unsigned int)rne_bf16(v.w) << 16);
    ((uint2*)xb)[i] = make_uint2(d0, d1);
}

__global__ __launch_bounds__(256) void cvt_w_kernel(const float* __restrict__ W1,
                                                    const float* __restrict__ Wmu,
                                                    const float* __restrict__ Wlog,
                                                    unsigned short* __restrict__ W1thi,
                                                    unsigned short* __restrict__ W1tlo,
                                                    unsigned short* __restrict__ Wcthi,
                                                    unsigned short* __restrict__ Wctlo) {
    int tid = blockIdx.x * 256 + threadIdx.x;   // 0..16383
    int n = tid & 127, k = tid >> 7;
    unsigned short h, l;
    float v1 = W1[k * 128 + n];
    split_bf16(v1, h, l);
    W1thi[n * 128 + k] = h;
    W1tlo[n * 128 + k] = l;
    float v2 = (n < 64) ? Wmu[k * 64 + n] : Wlog[k * 64 + (n - 64)];
    split_bf16(v2, h, l);
    Wcthi[n * 128 + k] = h;
    Wctlo[n * 128 + k] = l;
}

// ---------------------------------------------------------------------------
// Aggregation on bf16 rows (256B), quarter-wave (16 lanes x 16B) per node,
// 4 nodes/wave, unroll 4 -> 16 row-gathers in flight per wave.
// Weight recomputed on the fly: w = dinv[node] * dinv[src].
// Output: bf16 hi/lo split (feeds MFMA GEMM).
// ---------------------------------------------------------------------------
__global__ __launch_bounds__(256) void agg_bf16_kernel(const unsigned short* __restrict__ X,
                                                       const int* __restrict__ offsets,
                                                       const int* __restrict__ csr_src,
                                                       const float* __restrict__ dinv,
                                                       unsigned short* __restrict__ Yhi,
                                                       unsigned short* __restrict__ Ylo,
                                                       int n) {
    int node = (blockIdx.x << 4) + (threadIdx.x >> 4);
    int l16  = threadIdx.x & 15;
    if (node >= n) return;
    const uint4* X16 = (const uint4*)X;   // row = 16 uint4 (128 bf16)

    float dv = dinv[node];
    float sw = dv * dv;
    float a[8];
    {
        uint4 xv = X16[(size_t)node * 16 + l16];
        float f0, f1;
        unpack2(xv.x, f0, f1); a[0] = sw * f0; a[1] = sw * f1;
        unpack2(xv.y, f0, f1); a[2] = sw * f0; a[3] = sw * f1;
        unpack2(xv.z, f0, f1); a[4] = sw * f0; a[5] = sw * f1;
        unpack2(xv.w, f0, f1); a[6] = sw * f0; a[7] = sw * f1;
    }

    int beg = offsets[node], end = offsets[node + 1];
    int i = beg;
    for (; i + 4 <= end; i += 4) {
        int s0 = csr_src[i];
        int s1 = csr_src[i + 1];
        int s2 = csr_src[i + 2];
        int s3 = csr_src[i + 3];
        uint4 m0 = X16[(size_t)s0 * 16 + l16];
        uint4 m1 = X16[(size_t)s1 * 16 + l16];
        uint4 m2 = X16[(size_t)s2 * 16 + l16];
        uint4 m3 = X16[(size_t)s3 * 16 + l16];
        float w0 = dv * dinv[s0];
        float w1 = dv * dinv[s1];
        float w2 = dv * dinv[s2];
        float w3 = dv * dinv[s3];
        acc_row(m0, w0, a);
        acc_row(m1, w1, a);
        acc_row(m2, w2, a);
        acc_row(m3, w3, a);
    }
    for (; i < end; i++) {
        int s = csr_src[i];
        uint4 m = X16[(size_t)s * 16 + l16];
        acc_row(m, dv * dinv[s], a);
    }

    unsigned short h[8], l[8];
#pragma unroll
    for (int j = 0; j < 8; j++) split_bf16(a[j], h[j], l[j]);
    uint4 ph, pl;
    ph.x = (unsigned int)h[0] | ((unsigned int)h[1] << 16);
    ph.y = (unsigned int)h[2] | ((unsigned int)h[3] << 16);
    ph.z = (unsigned int)h[4] | ((unsigned int)h[5] << 16);
    ph.w = (unsigned int)h[6] | ((unsigned int)h[7] << 16);
    pl.x = (unsigned int)l[0] | ((unsigned int)l[1] << 16);
    pl.y = (unsigned int)l[2] | ((unsigned int)l[3] << 16);
    pl.z = (unsigned int)l[4] | ((unsigned int)l[5] << 16);
    pl.w = (unsigned int)l[6] | ((unsigned int)l[7] << 16);
    ((uint4*)Yhi)[(size_t)node * 16 + l16] = ph;
    ((uint4*)Ylo)[(size_t)node * 16 + l16] = pl;
}

// ---------------------------------------------------------------------------
// MFMA GEMM: D[M,128] = (Ahi+Alo)[M,128] @ W[128,128], W pre-split/transposed.
// 3-product split: D = Ah*Wh + Ah*Wl + Al*Wh (fp32 accumulate).
// Block = 64 rows x 128 cols, 4 waves. Each wave: ALL 64 rows x 32 cols
// (4 row-tiles x 2 col-tiles). A-frags live in regs; each W-frag load feeds
// 4 row-tiles (48 MFMA per 8 B-loads) with 4 independent acc chains for ILP.
// EPI 0: h = bf16(relu(D + b1)) -> H
// EPI 1: cols<64 -> out[row*64+c]+bmu ; cols>=64 -> out[N*64+row*64+c-64]+blog
// ---------------------------------------------------------------------------
template <int EPI>
__global__ __launch_bounds__(256) void mfma_gemm_kernel(const unsigned short* __restrict__ Ahi,
                                                        const unsigned short* __restrict__ Alo,
                                                        const unsigned short* __restrict__ Wthi,
                                                        const unsigned short* __restrict__ Wtlo,
                                                        const float* __restrict__ ba,
                                                        const float* __restrict__ bb,
                                                        unsigned short* __restrict__ H,
                                                        float* __restrict__ out, int M) {
    int wave = threadIdx.x >> 6;
    int lane = threadIdx.x & 63;
    int m16  = lane & 15;       // A row within tile / D col within tile
    int kg   = lane >> 4;       // 0..3
    int rbase = blockIdx.x * 64;

    bf16x8 ah[4][4], al[4][4];
#pragma unroll
    for (int rt = 0; rt < 4; rt++) {
        int arow = rbase + rt * 16 + m16;
        bool rok = arow < M;
        const unsigned short* arh = Ahi + (size_t)(rok ? arow : 0) * 128;
        const unsigned short* arl = Alo + (size_t)(rok ? arow : 0) * 128;
#pragma unroll
        for (int kt = 0; kt < 4; kt++) {
            bf16x8 vh = *(const bf16x8*)(const void*)(arh + kt * 32 + kg * 8);
            bf16x8 vl = *(const bf16x8*)(const void*)(arl + kt * 32 + kg * 8);
            ah[rt][kt] = rok ? vh : (bf16x8)(short)0;
            al[rt][kt] = rok ? vl : (bf16x8)(short)0;
        }
    }

#pragma unroll
    for (int ntl = 0; ntl < 2; ntl++) {
        int wnt = wave * 2 + ntl;   // col tile 0..7
        const unsigned short* wrh = Wthi + (size_t)(wnt * 16 + m16) * 128;
        const unsigned short* wrl = Wtlo + (size_t)(wnt * 16 + m16) * 128;
        bf16x8 bh[4], bl[4];
#pragma unroll
        for (int kt = 0; kt < 4; kt++) {
            bh[kt] = *(const bf16x8*)(const void*)(wrh + kt * 32 + kg * 8);
            bl[kt] = *(const bf16x8*)(const void*)(wrl + kt * 32 + kg * 8);
        }
        f32x4 acc[4];
#pragma unroll
        for (int rt = 0; rt < 4; rt++) acc[rt] = (f32x4){0.f, 0.f, 0.f, 0.f};
#pragma unroll
        for (int kt = 0; kt < 4; kt++) {
#pragma unroll
            for (int rt = 0; rt < 4; rt++) {
                acc[rt] = __builtin_amdgcn_mfma_f32_16x16x32_bf16(ah[rt][kt], bh[kt], acc[rt], 0, 0, 0);
                acc[rt] = __builtin_amdgcn_mfma_f32_16x16x32_bf16(ah[rt][kt], bl[kt], acc[rt], 0, 0, 0);
                acc[rt] = __builtin_amdgcn_mfma_f32_16x16x32_bf16(al[rt][kt], bh[kt], acc[rt], 0, 0, 0);
            }
        }
        // epilogue: D[row = rbase + rt*16 + kg*4 + j][col = wnt*16 + m16]
        int n0 = wnt * 16 + m16;
        if (EPI == 0) {
            float b = ba[n0];
#pragma unroll
            for (int rt = 0; rt < 4; rt++) {
#pragma unroll
                for (int j = 0; j < 4; j++) {
                    int r = rbase + rt * 16 + kg * 4 + j;
                    if (r < M) H[(size_t)r * 128 + n0] = rne_bf16(fmaxf(acc[rt][j] + b, 0.f));
                }
            }
        } else {
            bool is_mu = (n0 < 64);
            int c = is_mu ? n0 : (n0 - 64);
            float b = is_mu ? ba[c] : bb[c];
            size_t obase = is_mu ? 0 : (size_t)N_NODES * 64;
#pragma unroll
            for (int rt = 0; rt < 4; rt++) {
#pragma unroll
                for (int j = 0; j < 4; j++) {
                    int r = rbase + rt * 16 + kg * 4 + j;
                    if (r < M) out[obase + (size_t)r * 64 + c] = acc[rt][j] + b;
                }
            }
        }
    }
}

// ---------------------------------------------------------------------------
extern "C" void kernel_launch(void* const* d_in, const int* in_sizes, int n_in,
                              void* d_out, int out_size, void* d_ws, size_t ws_size,
                              hipStream_t stream) {
    const float* x    = (const float*)d_in[0];
    const int*   ei   = (const int*)d_in[1];
    const float* W1   = (const float*)d_in[2];
    const float* b1   = (const float*)d_in[3];
    const float* Wmu  = (const float*)d_in[4];
    const float* bmu  = (const float*)d_in[5];
    const float* Wlog = (const float*)d_in[6];
    const float* blog = (const float*)d_in[7];
    float* out = (float*)d_out;

    const int N = N_NODES;
    const int E = in_sizes[1] / 2;
    const int* src = ei;
    const int* dst = ei + E;

    auto align256 = [](size_t v) { return (v + 255) & ~(size_t)255; };
    char* ws = (char*)d_ws;
    size_t off = 0;
    int*   counts  = (int*)(ws + off);  off += align256((size_t)NPAD * 4);
    int*   offsets = (int*)(ws + off);  off += align256((size_t)NPAD * 4);
    int*   local   = (int*)(ws + off);  off += align256((size_t)NPAD * 4);
    int*   bsums   = (int*)(ws + off);  off += align256(256 * 4);
    int*   boffs   = (int*)(ws + off);  off += align256(256 * 4);
    float* dinv    = (float*)(ws + off); off += align256((size_t)N * 4);
    int*   rank    = (int*)(ws + off);  off += align256((size_t)E * 4);
    int*   csr_src = (int*)(ws + off);  off += align256((size_t)E * 4);
    unsigned short* xb    = (unsigned short*)(ws + off); off += align256((size_t)N * FDIM * 2);
    unsigned short* Hb    = (unsigned short*)(ws + off); off += align256((size_t)N * FDIM * 2);
    unsigned short* Aghi  = (unsigned short*)(ws + off); off += align256((size_t)N * FDIM * 2);
    unsigned short* Aglo  = (unsigned short*)(ws + off); off += align256((size_t)N * FDIM * 2);
    unsigned short* W1thi = (unsigned short*)(ws + off); off += align256(128 * 128 * 2);
    unsigned short* W1tlo = (unsigned short*)(ws + off); off += align256(128 * 128 * 2);
    unsigned short* Wcthi = (unsigned short*)(ws + off); off += align256(128 * 128 * 2);
    unsigned short* Wctlo = (unsigned short*)(ws + off); off += align256(128 * 128 * 2);

    // 1. CSR + dinv (rank captured during count; scatter is atomic-free)
    zero_kernel<<<(NPAD / 4 + 255) / 256, 256, 0, stream>>>((int4*)counts, NPAD / 4);
    count_kernel<<<(E + 255) / 256, 256, 0, stream>>>(dst, counts, rank, E);
    dinv_kernel<<<(N + 255) / 256, 256, 0, stream>>>(counts, dinv, N);
    scan_local_kernel<<<SCAN_NB, 256, 0, stream>>>(counts, local, bsums);
    scan_bsums_kernel<<<1, 64, 0, stream>>>(bsums, boffs, SCAN_NB);
    scan_add_kernel<<<SCAN_NB, 256, 0, stream>>>(local, boffs, offsets);
    scatter_kernel<<<(E + 255) / 256, 256, 0, stream>>>(src, dst, rank, offsets, csr_src, E);

    // 2. prep conversions
    cvt_x_kernel<<<(N * FDIM / 4 + 255) / 256, 256, 0, stream>>>(x, xb, N * FDIM / 4);
    cvt_w_kernel<<<64, 256, 0, stream>>>(W1, Wmu, Wlog, W1thi, W1tlo, Wcthi, Wctlo);

    // 3. agg1: (A x) -> hi/lo split
    agg_bf16_kernel<<<(N + 15) / 16, 256, 0, stream>>>(xb, offsets, csr_src, dinv, Aghi, Aglo, N);

    // 4. h = bf16(relu((Ax) @ W1 + b1))
    mfma_gemm_kernel<0><<<(N + 63) / 64, 256, 0, stream>>>(Aghi, Aglo, W1thi, W1tlo,
                                                           b1, nullptr, Hb, nullptr, N);

    // 5. agg2: (A h) -> hi/lo split
    agg_bf16_kernel<<<(N + 15) / 16, 256, 0, stream>>>(Hb, offsets, csr_src, dinv, Aghi, Aglo, N);

    // 6. [mu | logstd] = (Ah) @ [Wmu|Wlog] + bias -> d_out
    mfma_gemm_kernel<1><<<(N + 63) / 64, 256, 0, stream>>>(Aghi, Aglo, Wcthi, Wctlo,
                                                           bmu, blog, nullptr, out, N);
}

// Round 8
// 176.308 us; speedup vs baseline: 2.1000x; 1.1398x over previous
//
#include <hip/hip_runtime.h>
#include <hip/hip_bf16.h>

#define N_NODES 50000
#define FDIM 128
#define NPAD 50176      // 49 * 1024, covers N_NODES+1
#define SCAN_NB 49

typedef short bf16x8 __attribute__((ext_vector_type(8)));
typedef float f32x4  __attribute__((ext_vector_type(4)));

__device__ __forceinline__ unsigned short rne_bf16(float f) {
    unsigned int u = __float_as_uint(f);
    unsigned int r = (u + 0x7FFFu + ((u >> 16) & 1u)) >> 16;
    return (unsigned short)r;
}
__device__ __forceinline__ float bf16_to_f32(unsigned short s) {
    return __uint_as_float(((unsigned int)s) << 16);
}
__device__ __forceinline__ void split_bf16(float f, unsigned short& h, unsigned short& l) {
    h = rne_bf16(f);
    l = rne_bf16(f - bf16_to_f32(h));
}
__device__ __forceinline__ void unpack2(unsigned int d, float& f0, float& f1) {
    f0 = __uint_as_float(d << 16);
    f1 = __uint_as_float(d & 0xFFFF0000u);
}
// acc[0..7] += wt * row(m)  (8 bf16 in a uint4)
__device__ __forceinline__ void acc_row(const uint4& m, float wt, float* a) {
    float f0, f1;
    unpack2(m.x, f0, f1); a[0] += wt * f0; a[1] += wt * f1;
    unpack2(m.y, f0, f1); a[2] += wt * f0; a[3] += wt * f1;
    unpack2(m.z, f0, f1); a[4] += wt * f0; a[5] += wt * f1;
    unpack2(m.w, f0, f1); a[6] += wt * f0; a[7] += wt * f1;
}

// ---------------------------------------------------------------------------
__global__ __launch_bounds__(256) void zero_kernel(int4* __restrict__ p, int n4) {
    int i = blockIdx.x * 256 + threadIdx.x;
    if (i < n4) p[i] = make_int4(0, 0, 0, 0);
}

// CSR build: count in-degree AND capture each edge's rank within its dst
__global__ __launch_bounds__(256) void count_kernel(const int* __restrict__ dst,
                                                    int* __restrict__ counts,
                                                    int* __restrict__ rank, int E) {
    int e = blockIdx.x * blockDim.x + threadIdx.x;
    if (e < E) rank[e] = atomicAdd(&counts[dst[e]], 1);
}

// local scan + dinv fused (reads counts once)
__global__ __launch_bounds__(256) void scan_local_kernel(const int* __restrict__ counts,
                                                         int* __restrict__ local,
                                                         int* __restrict__ bsums,
                                                         float* __restrict__ dinv) {
    int t    = threadIdx.x;
    int lane = t & 63;
    int wid  = t >> 6;
    int base = blockIdx.x * 1024 + t * 4;
    int4 v = *(const int4*)(counts + base);
    float4 dv;
    dv.x = rsqrtf((float)v.x + 1.0f);
    dv.y = rsqrtf((float)v.y + 1.0f);
    dv.z = rsqrtf((float)v.z + 1.0f);
    dv.w = rsqrtf((float)v.w + 1.0f);
    *(float4*)(dinv + base) = dv;
    int s = v.x + v.y + v.z + v.w;
    int incl = s;
#pragma unroll
    for (int off = 1; off < 64; off <<= 1) {
        int u = __shfl_up(incl, off, 64);
        if (lane >= off) incl += u;
    }
    __shared__ int wtot[4];
    if (lane == 63) wtot[wid] = incl;
    __syncthreads();
    int wbase = 0;
#pragma unroll
    for (int w = 0; w < 3; w++) wbase += (w < wid) ? wtot[w] : 0;
    int excl = wbase + incl - s;
    int4 o;
    o.x = excl;
    o.y = excl + v.x;
    o.z = o.y + v.y;
    o.w = o.z + v.z;
    *(int4*)(local + base) = o;
    if (t == 255) bsums[blockIdx.x] = wbase + incl;
}

__global__ __launch_bounds__(64) void scan_bsums_kernel(const int* __restrict__ bsums,
                                                        int* __restrict__ boffs, int nb) {
    int lane = threadIdx.x;
    int v = (lane < nb) ? bsums[lane] : 0;
    int incl = v;
#pragma unroll
    for (int off = 1; off < 64; off <<= 1) {
        int u = __shfl_up(incl, off, 64);
        if (lane >= off) incl += u;
    }
    if (lane < nb) boffs[lane] = incl - v;
}

__global__ __launch_bounds__(256) void scan_add_kernel(const int* __restrict__ local,
                                                       const int* __restrict__ boffs,
                                                       int* __restrict__ offsets) {
    int base = blockIdx.x * 1024 + threadIdx.x * 4;
    int bo = boffs[blockIdx.x];
    int4 v = *(const int4*)(local + base);
    v.x += bo; v.y += bo; v.z += bo; v.w += bo;
    *(int4*)(offsets + base) = v;
}

// atomic-free scatter: pos = offsets[dst] + rank
__global__ __launch_bounds__(256) void scatter_kernel(const int* __restrict__ src,
                                                      const int* __restrict__ dst,
                                                      const int* __restrict__ rank,
                                                      const int* __restrict__ offsets,
                                                      int* __restrict__ csr_src, int E) {
    int e = blockIdx.x * blockDim.x + threadIdx.x;
    if (e < E) {
        int d = dst[e];
        int pos = offsets[d] + rank[e];
        csr_src[pos] = src[e];
    }
}

// ---------------------------------------------------------------------------
// Prep: x fp32 -> bf16; W -> transposed bf16 hi/lo splits, PRE-SWIZZLED
// (idx ^= (n&7)<<3) so the GEMM's linear LDS stage + swizzled ds_read is
// bank-conflict-light (G4 XOR-swizzle; swizzle applied global-side, m104).
// ---------------------------------------------------------------------------
__global__ __launch_bounds__(256) void cvt_x_kernel(const float* __restrict__ x,
                                                    unsigned short* __restrict__ xb, int n4) {
    int i = blockIdx.x * blockDim.x + threadIdx.x;
    if (i >= n4) return;
    float4 v = ((const float4*)x)[i];
    unsigned int d0 = (unsigned int)rne_bf16(v.x) | ((unsigned int)rne_bf16(v.y) << 16);
    unsigned int d1 = (unsigned int)rne_bf16(v.z) | ((unsigned int)rne_bf16(v.w) << 16);
    ((uint2*)xb)[i] = make_uint2(d0, d1);
}

__global__ __launch_bounds__(256) void cvt_w_kernel(const float* __restrict__ W1,
                                                    const float* __restrict__ Wmu,
                                                    const float* __restrict__ Wlog,
                                                    unsigned short* __restrict__ W1thi,
                                                    unsigned short* __restrict__ W1tlo,
                                                    unsigned short* __restrict__ Wcthi,
                                                    unsigned short* __restrict__ Wctlo) {
    int tid = blockIdx.x * 256 + threadIdx.x;   // 0..16383
    int n = tid & 127, k = tid >> 7;
    int swzidx = (n * 128 + k) ^ ((n & 7) << 3);
    unsigned short h, l;
    float v1 = W1[k * 128 + n];
    split_bf16(v1, h, l);
    W1thi[swzidx] = h;
    W1tlo[swzidx] = l;
    float v2 = (n < 64) ? Wmu[k * 64 + n] : Wlog[k * 64 + (n - 64)];
    split_bf16(v2, h, l);
    Wcthi[swzidx] = h;
    Wctlo[swzidx] = l;
}

// ---------------------------------------------------------------------------
// Aggregation on bf16 rows (256B), quarter-wave (16 lanes x 16B) per node,
// 4 nodes/wave, unroll 4. Weight on the fly: w = dinv[node]*dinv[src].
// ---------------------------------------------------------------------------
__global__ __launch_bounds__(256) void agg_bf16_kernel(const unsigned short* __restrict__ X,
                                                       const int* __restrict__ offsets,
                                                       const int* __restrict__ csr_src,
                                                       const float* __restrict__ dinv,
                                                       unsigned short* __restrict__ Yhi,
                                                       unsigned short* __restrict__ Ylo,
                                                       int n) {
    int node = (blockIdx.x << 4) + (threadIdx.x >> 4);
    int l16  = threadIdx.x & 15;
    if (node >= n) return;
    const uint4* X16 = (const uint4*)X;

    float dv = dinv[node];
    float sw = dv * dv;
    float a[8];
    {
        uint4 xv = X16[(size_t)node * 16 + l16];
        float f0, f1;
        unpack2(xv.x, f0, f1); a[0] = sw * f0; a[1] = sw * f1;
        unpack2(xv.y, f0, f1); a[2] = sw * f0; a[3] = sw * f1;
        unpack2(xv.z, f0, f1); a[4] = sw * f0; a[5] = sw * f1;
        unpack2(xv.w, f0, f1); a[6] = sw * f0; a[7] = sw * f1;
    }

    int beg = offsets[node], end = offsets[node + 1];
    int i = beg;
    for (; i + 4 <= end; i += 4) {
        int s0 = csr_src[i];
        int s1 = csr_src[i + 1];
        int s2 = csr_src[i + 2];
        int s3 = csr_src[i + 3];
        uint4 m0 = X16[(size_t)s0 * 16 + l16];
        uint4 m1 = X16[(size_t)s1 * 16 + l16];
        uint4 m2 = X16[(size_t)s2 * 16 + l16];
        uint4 m3 = X16[(size_t)s3 * 16 + l16];
        float w0 = dv * dinv[s0];
        float w1 = dv * dinv[s1];
        float w2 = dv * dinv[s2];
        float w3 = dv * dinv[s3];
        acc_row(m0, w0, a);
        acc_row(m1, w1, a);
        acc_row(m2, w2, a);
        acc_row(m3, w3, a);
    }
    for (; i < end; i++) {
        int s = csr_src[i];
        uint4 m = X16[(size_t)s * 16 + l16];
        acc_row(m, dv * dinv[s], a);
    }

    unsigned short h[8], l[8];
#pragma unroll
    for (int j = 0; j < 8; j++) split_bf16(a[j], h[j], l[j]);
    uint4 ph, pl;
    ph.x = (unsigned int)h[0] | ((unsigned int)h[1] << 16);
    ph.y = (unsigned int)h[2] | ((unsigned int)h[3] << 16);
    ph.z = (unsigned int)h[4] | ((unsigned int)h[5] << 16);
    ph.w = (unsigned int)h[6] | ((unsigned int)h[7] << 16);
    pl.x = (unsigned int)l[0] | ((unsigned int)l[1] << 16);
    pl.y = (unsigned int)l[2] | ((unsigned int)l[3] << 16);
    pl.z = (unsigned int)l[4] | ((unsigned int)l[5] << 16);
    pl.w = (unsigned int)l[6] | ((unsigned int)l[7] << 16);
    ((uint4*)Yhi)[(size_t)node * 16 + l16] = ph;
    ((uint4*)Ylo)[(size_t)node * 16 + l16] = pl;
}

// ---------------------------------------------------------------------------
// MFMA GEMM, W-in-LDS: D[M,128] = (Ahi+Alo) @ W, 3-product bf16 split.
// Block = 64 rows, 4 waves (16 rows each). W hi+lo (64 KB) staged to LDS
// once per block from the PRE-SWIZZLED global buffers (linear copy).
// Per wave: 8 VMEM A-loads + 64 ds_read_b128 + 96 MFMA (12:1 MFMA:VMEM).
// Col-tiles processed in pairs -> 2 independent acc chains for ILP.
// ---------------------------------------------------------------------------
template <int EPI>
__global__ __launch_bounds__(256) void mfma_gemm_kernel(const unsigned short* __restrict__ Ahi,
                                                        const unsigned short* __restrict__ Alo,
                                                        const unsigned short* __restrict__ Wthi,
                                                        const unsigned short* __restrict__ Wtlo,
                                                        const float* __restrict__ ba,
                                                        const float* __restrict__ bb,
                                                        unsigned short* __restrict__ H,
                                                        float* __restrict__ out, int M) {
    __shared__ unsigned short Wlds[32768];   // [0,16K) ushorts hi, [16K,32K) lo

    int t    = threadIdx.x;
    int wave = t >> 6;
    int lane = t & 63;
    int m16  = lane & 15;
    int kg   = lane >> 4;

    // stage W (linear; source is pre-swizzled)
    {
        const uint4* gh = (const uint4*)Wthi;
        const uint4* gl = (const uint4*)Wtlo;
        uint4* lds4 = (uint4*)Wlds;
#pragma unroll
        for (int i = 0; i < 8; i++) lds4[i * 256 + t] = gh[i * 256 + t];
#pragma unroll
        for (int i = 0; i < 8; i++) lds4[2048 + i * 256 + t] = gl[i * 256 + t];
    }

    // A fragments for this wave's 16 rows (overlap with staging latency)
    int rbase = blockIdx.x * 64 + wave * 16;
    int arow  = rbase + m16;
    bool rok  = arow < M;
    const unsigned short* arh = Ahi + (size_t)(rok ? arow : 0) * 128;
    const unsigned short* arl = Alo + (size_t)(rok ? arow : 0) * 128;
    bf16x8 ah[4], al[4];
#pragma unroll
    for (int kt = 0; kt < 4; kt++) {
        bf16x8 vh = *(const bf16x8*)(const void*)(arh + kt * 32 + kg * 8);
        bf16x8 vl = *(const bf16x8*)(const void*)(arl + kt * 32 + kg * 8);
        ah[kt] = rok ? vh : (bf16x8)(short)0;
        al[kt] = rok ? vl : (bf16x8)(short)0;
    }
    __syncthreads();

    int swz = (m16 & 7) << 3;
#pragma unroll
    for (int np = 0; np < 4; np++) {
        int nt0 = np * 2, nt1 = np * 2 + 1;
        f32x4 acc0 = {0.f, 0.f, 0.f, 0.f};
        f32x4 acc1 = {0.f, 0.f, 0.f, 0.f};
#pragma unroll
        for (int kt = 0; kt < 4; kt++) {
            int i0 = (((nt0 * 16 + m16) * 128) + kt * 32 + kg * 8) ^ swz;
            int i1 = (((nt1 * 16 + m16) * 128) + kt * 32 + kg * 8) ^ swz;
            bf16x8 bh0 = *(const bf16x8*)(const void*)&Wlds[i0];
            bf16x8 bl0 = *(const bf16x8*)(const void*)&Wlds[16384 + i0];
            bf16x8 bh1 = *(const bf16x8*)(const void*)&Wlds[i1];
            bf16x8 bl1 = *(const bf16x8*)(const void*)&Wlds[16384 + i1];
            acc0 = __builtin_amdgcn_mfma_f32_16x16x32_bf16(ah[kt], bh0, acc0, 0, 0, 0);
            acc1 = __builtin_amdgcn_mfma_f32_16x16x32_bf16(ah[kt], bh1, acc1, 0, 0, 0);
            acc0 = __builtin_amdgcn_mfma_f32_16x16x32_bf16(ah[kt], bl0, acc0, 0, 0, 0);
            acc1 = __builtin_amdgcn_mfma_f32_16x16x32_bf16(ah[kt], bl1, acc1, 0, 0, 0);
            acc0 = __builtin_amdgcn_mfma_f32_16x16x32_bf16(al[kt], bh0, acc0, 0, 0, 0);
            acc1 = __builtin_amdgcn_mfma_f32_16x16x32_bf16(al[kt], bh1, acc1, 0, 0, 0);
        }
        // epilogue for both col-tiles: D[row=rbase+kg*4+j][col=nt*16+m16]
#pragma unroll
        for (int half = 0; half < 2; half++) {
            int nt = half ? nt1 : nt0;
            const f32x4& acc = half ? acc1 : acc0;
            int n0 = nt * 16 + m16;
            if (EPI == 0) {
                float b = ba[n0];
#pragma unroll
                for (int j = 0; j < 4; j++) {
                    int r = rbase + kg * 4 + j;
                    if (r < M) H[(size_t)r * 128 + n0] = rne_bf16(fmaxf(acc[j] + b, 0.f));
                }
            } else {
                bool is_mu = (n0 < 64);
                int c = is_mu ? n0 : (n0 - 64);
                float b = is_mu ? ba[c] : bb[c];
                size_t obase = is_mu ? 0 : (size_t)N_NODES * 64;
#pragma unroll
                for (int j = 0; j < 4; j++) {
                    int r = rbase + kg * 4 + j;
                    if (r < M) out[obase + (size_t)r * 64 + c] = acc[j] + b;
                }
            }
        }
    }
}

// ---------------------------------------------------------------------------
extern "C" void kernel_launch(void* const* d_in, const int* in_sizes, int n_in,
                              void* d_out, int out_size, void* d_ws, size_t ws_size,
                              hipStream_t stream) {
    const float* x    = (const float*)d_in[0];
    const int*   ei   = (const int*)d_in[1];
    const float* W1   = (const float*)d_in[2];
    const float* b1   = (const float*)d_in[3];
    const float* Wmu  = (const float*)d_in[4];
    const float* bmu  = (const float*)d_in[5];
    const float* Wlog = (const float*)d_in[6];
    const float* blog = (const float*)d_in[7];
    float* out = (float*)d_out;

    const int N = N_NODES;
    const int E = in_sizes[1] / 2;
    const int* src = ei;
    const int* dst = ei + E;

    auto align256 = [](size_t v) { return (v + 255) & ~(size_t)255; };
    char* ws = (char*)d_ws;
    size_t off = 0;
    int*   counts  = (int*)(ws + off);  off += align256((size_t)NPAD * 4);
    int*   offsets = (int*)(ws + off);  off += align256((size_t)NPAD * 4);
    int*   local   = (int*)(ws + off);  off += align256((size_t)NPAD * 4);
    int*   bsums   = (int*)(ws + off);  off += align256(256 * 4);
    int*   boffs   = (int*)(ws + off);  off += align256(256 * 4);
    float* dinv    = (float*)(ws + off); off += align256((size_t)NPAD * 4);
    int*   rank    = (int*)(ws + off);  off += align256((size_t)E * 4);
    int*   csr_src = (int*)(ws + off);  off += align256((size_t)E * 4);
    unsigned short* xb    = (unsigned short*)(ws + off); off += align256((size_t)N * FDIM * 2);
    unsigned short* Hb    = (unsigned short*)(ws + off); off += align256((size_t)N * FDIM * 2);
    unsigned short* Aghi  = (unsigned short*)(ws + off); off += align256((size_t)N * FDIM * 2);
    unsigned short* Aglo  = (unsigned short*)(ws + off); off += align256((size_t)N * FDIM * 2);
    unsigned short* W1thi = (unsigned short*)(ws + off); off += align256(128 * 128 * 2);
    unsigned short* W1tlo = (unsigned short*)(ws + off); off += align256(128 * 128 * 2);
    unsigned short* Wcthi = (unsigned short*)(ws + off); off += align256(128 * 128 * 2);
    unsigned short* Wctlo = (unsigned short*)(ws + off); off += align256(128 * 128 * 2);

    // 1. CSR + dinv
    zero_kernel<<<(NPAD / 4 + 255) / 256, 256, 0, stream>>>((int4*)counts, NPAD / 4);
    count_kernel<<<(E + 255) / 256, 256, 0, stream>>>(dst, counts, rank, E);
    scan_local_kernel<<<SCAN_NB, 256, 0, stream>>>(counts, local, bsums, dinv);
    scan_bsums_kernel<<<1, 64, 0, stream>>>(bsums, boffs, SCAN_NB);
    scan_add_kernel<<<SCAN_NB, 256, 0, stream>>>(local, boffs, offsets);
    scatter_kernel<<<(E + 255) / 256, 256, 0, stream>>>(src, dst, rank, offsets, csr_src, E);

    // 2. prep conversions
    cvt_x_kernel<<<(N * FDIM / 4 + 255) / 256, 256, 0, stream>>>(x, xb, N * FDIM / 4);
    cvt_w_kernel<<<64, 256, 0, stream>>>(W1, Wmu, Wlog, W1thi, W1tlo, Wcthi, Wctlo);

    // 3. agg1: (A x) -> hi/lo split
    agg_bf16_kernel<<<(N + 15) / 16, 256, 0, stream>>>(xb, offsets, csr_src, dinv, Aghi, Aglo, N);

    // 4. h = bf16(relu((Ax) @ W1 + b1))
    mfma_gemm_kernel<0><<<(N + 63) / 64, 256, 0, stream>>>(Aghi, Aglo, W1thi, W1tlo,
                                                           b1, nullptr, Hb, nullptr, N);

    // 5. agg2: (A h) -> hi/lo split
    agg_bf16_kernel<<<(N + 15) / 16, 256, 0, stream>>>(Hb, offsets, csr_src, dinv, Aghi, Aglo, N);

    // 6. [mu | logstd] = (Ah) @ [Wmu|Wlog] + bias -> d_out
    mfma_gemm_kernel<1><<<(N + 63) / 64, 256, 0, stream>>>(Aghi, Aglo, Wcthi, Wctlo,
                                                           bmu, blog, nullptr, out, N);
}

// Round 9
// 163.563 us; speedup vs baseline: 2.2637x; 1.0779x over previous
//
#include <hip/hip_runtime.h>
#include <hip/hip_bf16.h>

#define N_NODES 50000
#define FDIM 128
#define NPAD 50176      // 49 * 1024, covers N_NODES+1
#define SCAN_NB 49

typedef short bf16x8 __attribute__((ext_vector_type(8)));
typedef float f32x4  __attribute__((ext_vector_type(4)));

__device__ __forceinline__ unsigned short rne_bf16(float f) {
    unsigned int u = __float_as_uint(f);
    unsigned int r = (u + 0x7FFFu + ((u >> 16) & 1u)) >> 16;
    return (unsigned short)r;
}
__device__ __forceinline__ float bf16_to_f32(unsigned short s) {
    return __uint_as_float(((unsigned int)s) << 16);
}
__device__ __forceinline__ void split_bf16(float f, unsigned short& h, unsigned short& l) {
    h = rne_bf16(f);
    l = rne_bf16(f - bf16_to_f32(h));
}
__device__ __forceinline__ void unpack2(unsigned int d, float& f0, float& f1) {
    f0 = __uint_as_float(d << 16);
    f1 = __uint_as_float(d & 0xFFFF0000u);
}
// a[0..7] += row(m)  (8 bf16 in a uint4) -- pure add, weights pre-applied
__device__ __forceinline__ void add_row(const uint4& m, float* a) {
    float f0, f1;
    unpack2(m.x, f0, f1); a[0] += f0; a[1] += f1;
    unpack2(m.y, f0, f1); a[2] += f0; a[3] += f1;
    unpack2(m.z, f0, f1); a[4] += f0; a[5] += f1;
    unpack2(m.w, f0, f1); a[6] += f0; a[7] += f1;
}

// ---------------------------------------------------------------------------
__global__ __launch_bounds__(256) void zero_kernel(int4* __restrict__ p, int n4) {
    int i = blockIdx.x * 256 + threadIdx.x;
    if (i < n4) p[i] = make_int4(0, 0, 0, 0);
}

// CSR build: count in-degree AND capture each edge's rank within its dst
__global__ __launch_bounds__(256) void count_kernel(const int* __restrict__ dst,
                                                    int* __restrict__ counts,
                                                    int* __restrict__ rank, int E) {
    int e = blockIdx.x * blockDim.x + threadIdx.x;
    if (e < E) rank[e] = atomicAdd(&counts[dst[e]], 1);
}

// local scan over PADDED counts ((c+3)&~3) + dinv (0 for idx >= N)
__global__ __launch_bounds__(256) void scan_local_kernel(const int* __restrict__ counts,
                                                         int* __restrict__ local,
                                                         int* __restrict__ bsums,
                                                         float* __restrict__ dinv) {
    int t    = threadIdx.x;
    int lane = t & 63;
    int wid  = t >> 6;
    int base = blockIdx.x * 1024 + t * 4;
    int4 c = *(const int4*)(counts + base);
    float4 dv;
    dv.x = (base + 0 < N_NODES) ? rsqrtf((float)c.x + 1.0f) : 0.f;
    dv.y = (base + 1 < N_NODES) ? rsqrtf((float)c.y + 1.0f) : 0.f;
    dv.z = (base + 2 < N_NODES) ? rsqrtf((float)c.z + 1.0f) : 0.f;
    dv.w = (base + 3 < N_NODES) ? rsqrtf((float)c.w + 1.0f) : 0.f;
    *(float4*)(dinv + base) = dv;
    int4 v;   // padded counts
    v.x = (c.x + 3) & ~3;
    v.y = (c.y + 3) & ~3;
    v.z = (c.z + 3) & ~3;
    v.w = (c.w + 3) & ~3;
    int s = v.x + v.y + v.z + v.w;
    int incl = s;
#pragma unroll
    for (int off = 1; off < 64; off <<= 1) {
        int u = __shfl_up(incl, off, 64);
        if (lane >= off) incl += u;
    }
    __shared__ int wtot[4];
    if (lane == 63) wtot[wid] = incl;
    __syncthreads();
    int wbase = 0;
#pragma unroll
    for (int w = 0; w < 3; w++) wbase += (w < wid) ? wtot[w] : 0;
    int excl = wbase + incl - s;
    int4 o;
    o.x = excl;
    o.y = excl + v.x;
    o.z = o.y + v.y;
    o.w = o.z + v.z;
    *(int4*)(local + base) = o;
    if (t == 255) bsums[blockIdx.x] = wbase + incl;
}

// fused: bsums wave-scan + add block offset + write offsets + fill CSR pad
// slots with sentinel N_NODES + zero sentinel rows of xb/Hb (block 0)
__global__ __launch_bounds__(256) void scan_add_kernel(const int* __restrict__ local,
                                                       const int* __restrict__ bsums,
                                                       const int* __restrict__ counts,
                                                       int* __restrict__ offsets,
                                                       int* __restrict__ csr_src,
                                                       unsigned short* __restrict__ xb,
                                                       unsigned short* __restrict__ Hb) {
    int t = threadIdx.x;
    __shared__ int s_bo;
    if (t < 64) {
        int v = (t < blockIdx.x) ? bsums[t] : 0;   // blockIdx <= 48 < 64
#pragma unroll
        for (int off = 32; off; off >>= 1) v += __shfl_down(v, off, 64);
        if (t == 0) s_bo = v;
    }
    // zero sentinel row N of xb and Hb (128 ushorts = 64 uints each)
    if (blockIdx.x == 0 && t >= 64 && t < 128) {
        int k = t - 64;
        ((unsigned int*)(xb + (size_t)N_NODES * 128))[k] = 0u;
        ((unsigned int*)(Hb + (size_t)N_NODES * 128))[k] = 0u;
    }
    __syncthreads();
    int bo = s_bo;
    int base = blockIdx.x * 1024 + t * 4;
    int4 v = *(const int4*)(local + base);
    int4 c = *(const int4*)(counts + base);
    v.x += bo; v.y += bo; v.z += bo; v.w += bo;
    *(int4*)(offsets + base) = v;
    // pad fill: slots [off + count, off + paddedcount) = sentinel
    int off0[4] = {v.x, v.y, v.z, v.w};
    int cr[4]   = {c.x, c.y, c.z, c.w};
#pragma unroll
    for (int k = 0; k < 4; k++) {
        int b = off0[k] + cr[k];
        int e = off0[k] + ((cr[k] + 3) & ~3);
        for (int j = b; j < e; j++) csr_src[j] = N_NODES;
    }
}

// atomic-free scatter: pos = offsets[dst] + rank
__global__ __launch_bounds__(256) void scatter_kernel(const int* __restrict__ src,
                                                      const int* __restrict__ dst,
                                                      const int* __restrict__ rank,
                                                      const int* __restrict__ offsets,
                                                      int* __restrict__ csr_src, int E) {
    int e = blockIdx.x * blockDim.x + threadIdx.x;
    if (e < E) {
        int d = dst[e];
        int pos = offsets[d] + rank[e];
        csr_src[pos] = src[e];
    }
}

// ---------------------------------------------------------------------------
// Prep: xs = dinv[row]*x (fp32 product, single bf16 rounding)
// ---------------------------------------------------------------------------
__global__ __launch_bounds__(256) void cvt_x_kernel(const float* __restrict__ x,
                                                    const float* __restrict__ dinv,
                                                    unsigned short* __restrict__ xb, int n4) {
    int i = blockIdx.x * blockDim.x + threadIdx.x;
    if (i >= n4) return;
    float dv = dinv[i >> 5];   // 32 float4 per row
    float4 v = ((const float4*)x)[i];
    v.x *= dv; v.y *= dv; v.z *= dv; v.w *= dv;
    unsigned int d0 = (unsigned int)rne_bf16(v.x) | ((unsigned int)rne_bf16(v.y) << 16);
    unsigned int d1 = (unsigned int)rne_bf16(v.z) | ((unsigned int)rne_bf16(v.w) << 16);
    ((uint2*)xb)[i] = make_uint2(d0, d1);
}

__global__ __launch_bounds__(256) void cvt_w_kernel(const float* __restrict__ W1,
                                                    const float* __restrict__ Wmu,
                                                    const float* __restrict__ Wlog,
                                                    unsigned short* __restrict__ W1thi,
                                                    unsigned short* __restrict__ W1tlo,
                                                    unsigned short* __restrict__ Wcthi,
                                                    unsigned short* __restrict__ Wctlo) {
    int tid = blockIdx.x * 256 + threadIdx.x;   // 0..16383
    int n = tid & 127, k = tid >> 7;
    int swzidx = (n * 128 + k) ^ ((n & 7) << 3);
    unsigned short h, l;
    float v1 = W1[k * 128 + n];
    split_bf16(v1, h, l);
    W1thi[swzidx] = h;
    W1tlo[swzidx] = l;
    float v2 = (n < 64) ? Wmu[k * 64 + n] : Wlog[k * 64 + (n - 64)];
    split_bf16(v2, h, l);
    Wcthi[swzidx] = h;
    Wctlo[swzidx] = l;
}

// ---------------------------------------------------------------------------
// Aggregation: pure row-sum of pre-scaled bf16 rows, final *dinv[node].
// Quarter-wave (16 lanes x 16B) per node; int4 index loads (CSR 4-padded,
// sentinel row N_NODES is all-zero). Output: bf16 hi/lo split.
// ---------------------------------------------------------------------------
__global__ __launch_bounds__(256) void agg_bf16_kernel(const unsigned short* __restrict__ X,
                                                       const int* __restrict__ offsets,
                                                       const int* __restrict__ csr_src,
                                                       const float* __restrict__ dinv,
                                                       unsigned short* __restrict__ Yhi,
                                                       unsigned short* __restrict__ Ylo,
                                                       int n) {
    int node = (blockIdx.x << 4) + (threadIdx.x >> 4);
    int l16  = threadIdx.x & 15;
    if (node >= n) return;
    const uint4* X16 = (const uint4*)X;

    float a[8];
    {
        uint4 xv = X16[(size_t)node * 16 + l16];   // self row (pre-scaled)
        float f0, f1;
        unpack2(xv.x, f0, f1); a[0] = f0; a[1] = f1;
        unpack2(xv.y, f0, f1); a[2] = f0; a[3] = f1;
        unpack2(xv.z, f0, f1); a[4] = f0; a[5] = f1;
        unpack2(xv.w, f0, f1); a[6] = f0; a[7] = f1;
    }

    int beg = offsets[node], end = offsets[node + 1];
    int i = beg;
    for (; i + 8 <= end; i += 8) {
        int4 q0 = *(const int4*)(csr_src + i);
        int4 q1 = *(const int4*)(csr_src + i + 4);
        uint4 m0 = X16[(size_t)q0.x * 16 + l16];
        uint4 m1 = X16[(size_t)q0.y * 16 + l16];
        uint4 m2 = X16[(size_t)q0.z * 16 + l16];
        uint4 m3 = X16[(size_t)q0.w * 16 + l16];
        uint4 m4 = X16[(size_t)q1.x * 16 + l16];
        uint4 m5 = X16[(size_t)q1.y * 16 + l16];
        uint4 m6 = X16[(size_t)q1.z * 16 + l16];
        uint4 m7 = X16[(size_t)q1.w * 16 + l16];
        add_row(m0, a); add_row(m1, a); add_row(m2, a); add_row(m3, a);
        add_row(m4, a); add_row(m5, a); add_row(m6, a); add_row(m7, a);
    }
    if (i < end) {
        int4 q0 = *(const int4*)(csr_src + i);
        uint4 m0 = X16[(size_t)q0.x * 16 + l16];
        uint4 m1 = X16[(size_t)q0.y * 16 + l16];
        uint4 m2 = X16[(size_t)q0.z * 16 + l16];
        uint4 m3 = X16[(size_t)q0.w * 16 + l16];
        add_row(m0, a); add_row(m1, a); add_row(m2, a); add_row(m3, a);
    }

    float dv = dinv[node];
    unsigned short h[8], l[8];
#pragma unroll
    for (int j = 0; j < 8; j++) split_bf16(a[j] * dv, h[j], l[j]);
    uint4 ph, pl;
    ph.x = (unsigned int)h[0] | ((unsigned int)h[1] << 16);
    ph.y = (unsigned int)h[2] | ((unsigned int)h[3] << 16);
    ph.z = (unsigned int)h[4] | ((unsigned int)h[5] << 16);
    ph.w = (unsigned int)h[6] | ((unsigned int)h[7] << 16);
    pl.x = (unsigned int)l[0] | ((unsigned int)l[1] << 16);
    pl.y = (unsigned int)l[2] | ((unsigned int)l[3] << 16);
    pl.z = (unsigned int)l[4] | ((unsigned int)l[5] << 16);
    pl.w = (unsigned int)l[6] | ((unsigned int)l[7] << 16);
    ((uint4*)Yhi)[(size_t)node * 16 + l16] = ph;
    ((uint4*)Ylo)[(size_t)node * 16 + l16] = pl;
}

// ---------------------------------------------------------------------------
// MFMA GEMM, W-in-LDS: 512 threads / 8 waves / 128 rows per block.
// EPI 0: Hb = bf16(dinv[r] * relu(D + b1))   (pre-scaled for agg2)
// EPI 1: split mu/logstd halves to out.
// ---------------------------------------------------------------------------
template <int EPI>
__global__ __launch_bounds__(512) void mfma_gemm_kernel(const unsigned short* __restrict__ Ahi,
                                                        const unsigned short* __restrict__ Alo,
                                                        const unsigned short* __restrict__ Wthi,
                                                        const unsigned short* __restrict__ Wtlo,
                                                        const float* __restrict__ ba,
                                                        const float* __restrict__ bb,
                                                        const float* __restrict__ dinv,
                                                        unsigned short* __restrict__ H,
                                                        float* __restrict__ out, int M) {
    __shared__ unsigned short Wlds[32768];   // hi [0,16K) ushorts, lo [16K,32K)

    int t    = threadIdx.x;
    int wave = t >> 6;
    int lane = t & 63;
    int m16  = lane & 15;
    int kg   = lane >> 4;

    // stage W (linear; source is pre-swizzled). 4096 uint4 / 512 threads.
    {
        const uint4* gh = (const uint4*)Wthi;
        const uint4* gl = (const uint4*)Wtlo;
        uint4* lds4 = (uint4*)Wlds;
#pragma unroll
        for (int i = 0; i < 4; i++) lds4[i * 512 + t] = gh[i * 512 + t];
#pragma unroll
        for (int i = 0; i < 4; i++) lds4[2048 + i * 512 + t] = gl[i * 512 + t];
    }

    int rbase = blockIdx.x * 128 + wave * 16;
    int arow  = rbase + m16;
    bool rok  = arow < M;
    const unsigned short* arh = Ahi + (size_t)(rok ? arow : 0) * 128;
    const unsigned short* arl = Alo + (size_t)(rok ? arow : 0) * 128;
    bf16x8 ah[4], al[4];
#pragma unroll
    for (int kt = 0; kt < 4; kt++) {
        bf16x8 vh = *(const bf16x8*)(const void*)(arh + kt * 32 + kg * 8);
        bf16x8 vl = *(const bf16x8*)(const void*)(arl + kt * 32 + kg * 8);
        ah[kt] = rok ? vh : (bf16x8)(short)0;
        al[kt] = rok ? vl : (bf16x8)(short)0;
    }
    // per-lane output rows are rbase+kg*4+0..3 for all col tiles; hoist dinv
    float4 dv4 = {1.f, 1.f, 1.f, 1.f};
    if (EPI == 0) dv4 = *(const float4*)(dinv + rbase + kg * 4);
    __syncthreads();

    int swz = (m16 & 7) << 3;
#pragma unroll
    for (int np = 0; np < 4; np++) {
        int nt0 = np * 2, nt1 = np * 2 + 1;
        f32x4 acc0 = {0.f, 0.f, 0.f, 0.f};
        f32x4 acc1 = {0.f, 0.f, 0.f, 0.f};
#pragma unroll
        for (int kt = 0; kt < 4; kt++) {
            int i0 = (((nt0 * 16 + m16) * 128) + kt * 32 + kg * 8) ^ swz;
            int i1 = (((nt1 * 16 + m16) * 128) + kt * 32 + kg * 8) ^ swz;
            bf16x8 bh0 = *(const bf16x8*)(const void*)&Wlds[i0];
            bf16x8 bl0 = *(const bf16x8*)(const void*)&Wlds[16384 + i0];
            bf16x8 bh1 = *(const bf16x8*)(const void*)&Wlds[i1];
            bf16x8 bl1 = *(const bf16x8*)(const void*)&Wlds[16384 + i1];
            acc0 = __builtin_amdgcn_mfma_f32_16x16x32_bf16(ah[kt], bh0, acc0, 0, 0, 0);
            acc1 = __builtin_amdgcn_mfma_f32_16x16x32_bf16(ah[kt], bh1, acc1, 0, 0, 0);
            acc0 = __builtin_amdgcn_mfma_f32_16x16x32_bf16(ah[kt], bl0, acc0, 0, 0, 0);
            acc1 = __builtin_amdgcn_mfma_f32_16x16x32_bf16(ah[kt], bl1, acc1, 0, 0, 0);
            acc0 = __builtin_amdgcn_mfma_f32_16x16x32_bf16(al[kt], bh0, acc0, 0, 0, 0);
            acc1 = __builtin_amdgcn_mfma_f32_16x16x32_bf16(al[kt], bh1, acc1, 0, 0, 0);
        }
#pragma unroll
        for (int half = 0; half < 2; half++) {
            int nt = half ? nt1 : nt0;
            const f32x4& acc = half ? acc1 : acc0;
            int n0 = nt * 16 + m16;
            if (EPI == 0) {
                float b = ba[n0];
#pragma unroll
                for (int j = 0; j < 4; j++) {
                    int r = rbase + kg * 4 + j;
                    if (r < M) {
                        float v = fmaxf(acc[j] + b, 0.f) * dv4[j];
                        H[(size_t)r * 128 + n0] = rne_bf16(v);
                    }
                }
            } else {
                bool is_mu = (n0 < 64);
                int c = is_mu ? n0 : (n0 - 64);
                float b = is_mu ? ba[c] : bb[c];
                size_t obase = is_mu ? 0 : (size_t)N_NODES * 64;
#pragma unroll
                for (int j = 0; j < 4; j++) {
                    int r = rbase + kg * 4 + j;
                    if (r < M) out[obase + (size_t)r * 64 + c] = acc[j] + b;
                }
            }
        }
    }
}

// ---------------------------------------------------------------------------
extern "C" void kernel_launch(void* const* d_in, const int* in_sizes, int n_in,
                              void* d_out, int out_size, void* d_ws, size_t ws_size,
                              hipStream_t stream) {
    const float* x    = (const float*)d_in[0];
    const int*   ei   = (const int*)d_in[1];
    const float* W1   = (const float*)d_in[2];
    const float* b1   = (const float*)d_in[3];
    const float* Wmu  = (const float*)d_in[4];
    const float* bmu  = (const float*)d_in[5];
    const float* Wlog = (const float*)d_in[6];
    const float* blog = (const float*)d_in[7];
    float* out = (float*)d_out;

    const int N = N_NODES;
    const int E = in_sizes[1] / 2;
    const int Emax = E + 3 * N;   // CSR with 4-padding slack
    const int* src = ei;
    const int* dst = ei + E;

    auto align256 = [](size_t v) { return (v + 255) & ~(size_t)255; };
    char* ws = (char*)d_ws;
    size_t off = 0;
    int*   counts  = (int*)(ws + off);  off += align256((size_t)NPAD * 4);
    int*   offsets = (int*)(ws + off);  off += align256((size_t)NPAD * 4);
    int*   local   = (int*)(ws + off);  off += align256((size_t)NPAD * 4);
    int*   bsums   = (int*)(ws + off);  off += align256(256 * 4);
    float* dinv    = (float*)(ws + off); off += align256((size_t)NPAD * 4);
    int*   rank    = (int*)(ws + off);  off += align256((size_t)E * 4);
    int*   csr_src = (int*)(ws + off);  off += align256((size_t)Emax * 4);
    unsigned short* xb    = (unsigned short*)(ws + off); off += align256((size_t)(N + 1) * FDIM * 2);
    unsigned short* Hb    = (unsigned short*)(ws + off); off += align256((size_t)(N + 1) * FDIM * 2);
    unsigned short* Aghi  = (unsigned short*)(ws + off); off += align256((size_t)N * FDIM * 2);
    unsigned short* Aglo  = (unsigned short*)(ws + off); off += align256((size_t)N * FDIM * 2);
    unsigned short* W1thi = (unsigned short*)(ws + off); off += align256(128 * 128 * 2);
    unsigned short* W1tlo = (unsigned short*)(ws + off); off += align256(128 * 128 * 2);
    unsigned short* Wcthi = (unsigned short*)(ws + off); off += align256(128 * 128 * 2);
    unsigned short* Wctlo = (unsigned short*)(ws + off); off += align256(128 * 128 * 2);

    // 1. CSR + dinv (padded CSR, atomic-free scatter)
    zero_kernel<<<(NPAD / 4 + 255) / 256, 256, 0, stream>>>((int4*)counts, NPAD / 4);
    count_kernel<<<(E + 255) / 256, 256, 0, stream>>>(dst, counts, rank, E);
    scan_local_kernel<<<SCAN_NB, 256, 0, stream>>>(counts, local, bsums, dinv);
    scan_add_kernel<<<SCAN_NB, 256, 0, stream>>>(local, bsums, counts, offsets,
                                                 csr_src, xb, Hb);
    scatter_kernel<<<(E + 255) / 256, 256, 0, stream>>>(src, dst, rank, offsets, csr_src, E);

    // 2. prep: xs = dinv*x -> bf16 ; W splits (pre-swizzled)
    cvt_x_kernel<<<(N * FDIM / 4 + 255) / 256, 256, 0, stream>>>(x, dinv, xb, N * FDIM / 4);
    cvt_w_kernel<<<64, 256, 0, stream>>>(W1, Wmu, Wlog, W1thi, W1tlo, Wcthi, Wctlo);

    // 3. agg1: dv*(xs_v + sum xs_s) -> hi/lo split
    agg_bf16_kernel<<<(N + 15) / 16, 256, 0, stream>>>(xb, offsets, csr_src, dinv, Aghi, Aglo, N);

    // 4. Hb = bf16(dinv * relu((Ax) @ W1 + b1))
    mfma_gemm_kernel<0><<<(N + 127) / 128, 512, 0, stream>>>(Aghi, Aglo, W1thi, W1tlo,
                                                             b1, nullptr, dinv, Hb, nullptr, N);

    // 5. agg2: dv*(hs_v + sum hs_s) -> hi/lo split
    agg_bf16_kernel<<<(N + 15) / 16, 256, 0, stream>>>(Hb, offsets, csr_src, dinv, Aghi, Aglo, N);

    // 6. [mu | logstd] = (Ah) @ [Wmu|Wlog] + bias -> d_out
    mfma_gemm_kernel<1><<<(N + 127) / 128, 512, 0, stream>>>(Aghi, Aglo, Wcthi, Wctlo,
                                                             bmu, blog, nullptr, nullptr, out, N);
}

// Round 10
// 150.878 us; speedup vs baseline: 2.4540x; 1.0841x over previous
//
#include <hip/hip_runtime.h>
#include <hip/hip_bf16.h>

#define N_NODES 50000
#define FDIM 128
#define NPAD 50176      // 49 * 1024, covers N_NODES+1
#define SCAN_NB 49

typedef short bf16x8 __attribute__((ext_vector_type(8)));
typedef float f32x4  __attribute__((ext_vector_type(4)));

__device__ __forceinline__ unsigned short rne_bf16(float f) {
    unsigned int u = __float_as_uint(f);
    unsigned int r = (u + 0x7FFFu + ((u >> 16) & 1u)) >> 16;
    return (unsigned short)r;
}
__device__ __forceinline__ float bf16_to_f32(unsigned short s) {
    return __uint_as_float(((unsigned int)s) << 16);
}
__device__ __forceinline__ void split_bf16(float f, unsigned short& h, unsigned short& l) {
    h = rne_bf16(f);
    l = rne_bf16(f - bf16_to_f32(h));
}
__device__ __forceinline__ void unpack2(unsigned int d, float& f0, float& f1) {
    f0 = __uint_as_float(d << 16);
    f1 = __uint_as_float(d & 0xFFFF0000u);
}
// a[0..7] += row(m)  (8 bf16 in a uint4) -- pure add, weights pre-applied
__device__ __forceinline__ void add_row(const uint4& m, float* a) {
    float f0, f1;
    unpack2(m.x, f0, f1); a[0] += f0; a[1] += f1;
    unpack2(m.y, f0, f1); a[2] += f0; a[3] += f1;
    unpack2(m.z, f0, f1); a[4] += f0; a[5] += f1;
    unpack2(m.w, f0, f1); a[6] += f0; a[7] += f1;
}

// ---------------------------------------------------------------------------
// Fused: blocks [0,49) zero counts; blocks [49,113) split/transpose W
// (pre-swizzled idx ^= (n&7)<<3 for the GEMM's LDS bank-conflict-free read)
// ---------------------------------------------------------------------------
__global__ __launch_bounds__(256) void zero_cvtw_kernel(int4* __restrict__ counts4,
                                                        const float* __restrict__ W1,
                                                        const float* __restrict__ Wmu,
                                                        const float* __restrict__ Wlog,
                                                        unsigned short* __restrict__ W1thi,
                                                        unsigned short* __restrict__ W1tlo,
                                                        unsigned short* __restrict__ Wcthi,
                                                        unsigned short* __restrict__ Wctlo) {
    int b = blockIdx.x;
    if (b < SCAN_NB) {
        int i = b * 256 + threadIdx.x;
        if (i < NPAD / 4) counts4[i] = make_int4(0, 0, 0, 0);
        return;
    }
    int tid = (b - SCAN_NB) * 256 + threadIdx.x;   // 0..16383
    int n = tid & 127, k = tid >> 7;
    int swzidx = (n * 128 + k) ^ ((n & 7) << 3);
    unsigned short h, l;
    float v1 = W1[k * 128 + n];
    split_bf16(v1, h, l);
    W1thi[swzidx] = h;
    W1tlo[swzidx] = l;
    float v2 = (n < 64) ? Wmu[k * 64 + n] : Wlog[k * 64 + (n - 64)];
    split_bf16(v2, h, l);
    Wcthi[swzidx] = h;
    Wctlo[swzidx] = l;
}

// CSR build: count in-degree AND capture each edge's rank within its dst
__global__ __launch_bounds__(256) void count_kernel(const int* __restrict__ dst,
                                                    int* __restrict__ counts,
                                                    int* __restrict__ rank, int E) {
    int e = blockIdx.x * blockDim.x + threadIdx.x;
    if (e < E) rank[e] = atomicAdd(&counts[dst[e]], 1);
}

// local scan over PADDED counts ((c+3)&~3) + dinv (0 for idx >= N)
__global__ __launch_bounds__(256) void scan_local_kernel(const int* __restrict__ counts,
                                                         int* __restrict__ local,
                                                         int* __restrict__ bsums,
                                                         float* __restrict__ dinv) {
    int t    = threadIdx.x;
    int lane = t & 63;
    int wid  = t >> 6;
    int base = blockIdx.x * 1024 + t * 4;
    int4 c = *(const int4*)(counts + base);
    float4 dv;
    dv.x = (base + 0 < N_NODES) ? rsqrtf((float)c.x + 1.0f) : 0.f;
    dv.y = (base + 1 < N_NODES) ? rsqrtf((float)c.y + 1.0f) : 0.f;
    dv.z = (base + 2 < N_NODES) ? rsqrtf((float)c.z + 1.0f) : 0.f;
    dv.w = (base + 3 < N_NODES) ? rsqrtf((float)c.w + 1.0f) : 0.f;
    *(float4*)(dinv + base) = dv;
    int4 v;   // padded counts
    v.x = (c.x + 3) & ~3;
    v.y = (c.y + 3) & ~3;
    v.z = (c.z + 3) & ~3;
    v.w = (c.w + 3) & ~3;
    int s = v.x + v.y + v.z + v.w;
    int incl = s;
#pragma unroll
    for (int off = 1; off < 64; off <<= 1) {
        int u = __shfl_up(incl, off, 64);
        if (lane >= off) incl += u;
    }
    __shared__ int wtot[4];
    if (lane == 63) wtot[wid] = incl;
    __syncthreads();
    int wbase = 0;
#pragma unroll
    for (int w = 0; w < 3; w++) wbase += (w < wid) ? wtot[w] : 0;
    int excl = wbase + incl - s;
    int4 o;
    o.x = excl;
    o.y = excl + v.x;
    o.z = o.y + v.y;
    o.w = o.z + v.z;
    *(int4*)(local + base) = o;
    if (t == 255) bsums[blockIdx.x] = wbase + incl;
}

// fused: bsums wave-scan + add block offset + write offsets + fill CSR pad
// slots with sentinel N_NODES + zero sentinel rows of xb/Hb (block 0)
__global__ __launch_bounds__(256) void scan_add_kernel(const int* __restrict__ local,
                                                       const int* __restrict__ bsums,
                                                       const int* __restrict__ counts,
                                                       int* __restrict__ offsets,
                                                       int* __restrict__ csr_src,
                                                       unsigned short* __restrict__ xb,
                                                       unsigned short* __restrict__ Hb) {
    int t = threadIdx.x;
    __shared__ int s_bo;
    if (t < 64) {
        int v = (t < blockIdx.x) ? bsums[t] : 0;   // blockIdx <= 48 < 64
#pragma unroll
        for (int off = 32; off; off >>= 1) v += __shfl_down(v, off, 64);
        if (t == 0) s_bo = v;
    }
    // zero sentinel row N of xb and Hb (128 ushorts = 64 uints each)
    if (blockIdx.x == 0 && t >= 64 && t < 128) {
        int k = t - 64;
        ((unsigned int*)(xb + (size_t)N_NODES * 128))[k] = 0u;
        ((unsigned int*)(Hb + (size_t)N_NODES * 128))[k] = 0u;
    }
    __syncthreads();
    int bo = s_bo;
    int base = blockIdx.x * 1024 + t * 4;
    int4 v = *(const int4*)(local + base);
    int4 c = *(const int4*)(counts + base);
    v.x += bo; v.y += bo; v.z += bo; v.w += bo;
    *(int4*)(offsets + base) = v;
    // pad fill: slots [off + count, off + paddedcount) = sentinel
    int off0[4] = {v.x, v.y, v.z, v.w};
    int cr[4]   = {c.x, c.y, c.z, c.w};
#pragma unroll
    for (int k = 0; k < 4; k++) {
        int b = off0[k] + cr[k];
        int e = off0[k] + ((cr[k] + 3) & ~3);
        for (int j = b; j < e; j++) csr_src[j] = N_NODES;
    }
}

// ---------------------------------------------------------------------------
// Fused: blocks [0,scb) atomic-free scatter; blocks [scb, scb+cvb) cvt_x
// (xs = dinv[row]*x, single bf16 rounding)
// ---------------------------------------------------------------------------
__global__ __launch_bounds__(256) void scatter_cvtx_kernel(const int* __restrict__ src,
                                                           const int* __restrict__ dst,
                                                           const int* __restrict__ rank,
                                                           const int* __restrict__ offsets,
                                                           int* __restrict__ csr_src, int E,
                                                           int scb,
                                                           const float* __restrict__ x,
                                                           const float* __restrict__ dinv,
                                                           unsigned short* __restrict__ xb,
                                                           int n4) {
    int b = blockIdx.x;
    if (b < scb) {
        int e = b * 256 + threadIdx.x;
        if (e < E) {
            int d = dst[e];
            int pos = offsets[d] + rank[e];
            csr_src[pos] = src[e];
        }
        return;
    }
    int i = (b - scb) * 256 + threadIdx.x;
    if (i >= n4) return;
    float dv = dinv[i >> 5];   // 32 float4 per row
    float4 v = ((const float4*)x)[i];
    v.x *= dv; v.y *= dv; v.z *= dv; v.w *= dv;
    unsigned int d0 = (unsigned int)rne_bf16(v.x) | ((unsigned int)rne_bf16(v.y) << 16);
    unsigned int d1 = (unsigned int)rne_bf16(v.z) | ((unsigned int)rne_bf16(v.w) << 16);
    ((uint2*)xb)[i] = make_uint2(d0, d1);
}

// ---------------------------------------------------------------------------
// Aggregation: pure row-sum of pre-scaled bf16 rows, final *dinv[node].
// Quarter-wave (16 lanes x 16B) per node; int4 index loads (CSR 4-padded,
// sentinel row N_NODES is all-zero). Output: SINGLE bf16 plane.
// ---------------------------------------------------------------------------
__global__ __launch_bounds__(256) void agg_bf16_kernel(const unsigned short* __restrict__ X,
                                                       const int* __restrict__ offsets,
                                                       const int* __restrict__ csr_src,
                                                       const float* __restrict__ dinv,
                                                       unsigned short* __restrict__ Y,
                                                       int n) {
    int node = (blockIdx.x << 4) + (threadIdx.x >> 4);
    int l16  = threadIdx.x & 15;
    if (node >= n) return;
    const uint4* X16 = (const uint4*)X;

    float a[8];
    {
        uint4 xv = X16[(size_t)node * 16 + l16];   // self row (pre-scaled)
        float f0, f1;
        unpack2(xv.x, f0, f1); a[0] = f0; a[1] = f1;
        unpack2(xv.y, f0, f1); a[2] = f0; a[3] = f1;
        unpack2(xv.z, f0, f1); a[4] = f0; a[5] = f1;
        unpack2(xv.w, f0, f1); a[6] = f0; a[7] = f1;
    }

    int beg = offsets[node], end = offsets[node + 1];
    int i = beg;
    for (; i + 8 <= end; i += 8) {
        int4 q0 = *(const int4*)(csr_src + i);
        int4 q1 = *(const int4*)(csr_src + i + 4);
        uint4 m0 = X16[(size_t)q0.x * 16 + l16];
        uint4 m1 = X16[(size_t)q0.y * 16 + l16];
        uint4 m2 = X16[(size_t)q0.z * 16 + l16];
        uint4 m3 = X16[(size_t)q0.w * 16 + l16];
        uint4 m4 = X16[(size_t)q1.x * 16 + l16];
        uint4 m5 = X16[(size_t)q1.y * 16 + l16];
        uint4 m6 = X16[(size_t)q1.z * 16 + l16];
        uint4 m7 = X16[(size_t)q1.w * 16 + l16];
        add_row(m0, a); add_row(m1, a); add_row(m2, a); add_row(m3, a);
        add_row(m4, a); add_row(m5, a); add_row(m6, a); add_row(m7, a);
    }
    if (i < end) {
        int4 q0 = *(const int4*)(csr_src + i);
        uint4 m0 = X16[(size_t)q0.x * 16 + l16];
        uint4 m1 = X16[(size_t)q0.y * 16 + l16];
        uint4 m2 = X16[(size_t)q0.z * 16 + l16];
        uint4 m3 = X16[(size_t)q0.w * 16 + l16];
        add_row(m0, a); add_row(m1, a); add_row(m2, a); add_row(m3, a);
    }

    float dv = dinv[node];
    unsigned short h[8];
#pragma unroll
    for (int j = 0; j < 8; j++) h[j] = rne_bf16(a[j] * dv);
    uint4 ph;
    ph.x = (unsigned int)h[0] | ((unsigned int)h[1] << 16);
    ph.y = (unsigned int)h[2] | ((unsigned int)h[3] << 16);
    ph.z = (unsigned int)h[4] | ((unsigned int)h[5] << 16);
    ph.w = (unsigned int)h[6] | ((unsigned int)h[7] << 16);
    ((uint4*)Y)[(size_t)node * 16 + l16] = ph;
}

// ---------------------------------------------------------------------------
// MFMA GEMM, W-in-LDS: 512 threads / 8 waves / 128 rows per block.
// A single bf16; W hi/lo split -> D = A*Wh + A*Wl (fp32 accumulate).
// EPI 0: Hb = bf16(dinv[r] * relu(D + b1))   (pre-scaled for agg2)
// EPI 1: split mu/logstd halves to out.
// ---------------------------------------------------------------------------
template <int EPI>
__global__ __launch_bounds__(512) void mfma_gemm_kernel(const unsigned short* __restrict__ A,
                                                        const unsigned short* __restrict__ Wthi,
                                                        const unsigned short* __restrict__ Wtlo,
                                                        const float* __restrict__ ba,
                                                        const float* __restrict__ bb,
                                                        const float* __restrict__ dinv,
                                                        unsigned short* __restrict__ H,
                                                        float* __restrict__ out, int M) {
    __shared__ unsigned short Wlds[32768];   // hi [0,16K) ushorts, lo [16K,32K)

    int t    = threadIdx.x;
    int wave = t >> 6;
    int lane = t & 63;
    int m16  = lane & 15;
    int kg   = lane >> 4;

    // stage W (linear; source is pre-swizzled). 4096 uint4 / 512 threads.
    {
        const uint4* gh = (const uint4*)Wthi;
        const uint4* gl = (const uint4*)Wtlo;
        uint4* lds4 = (uint4*)Wlds;
#pragma unroll
        for (int i = 0; i < 4; i++) lds4[i * 512 + t] = gh[i * 512 + t];
#pragma unroll
        for (int i = 0; i < 4; i++) lds4[2048 + i * 512 + t] = gl[i * 512 + t];
    }

    int rbase = blockIdx.x * 128 + wave * 16;
    int arow  = rbase + m16;
    bool rok  = arow < M;
    const unsigned short* ar = A + (size_t)(rok ? arow : 0) * 128;
    bf16x8 af[4];
#pragma unroll
    for (int kt = 0; kt < 4; kt++) {
        bf16x8 v = *(const bf16x8*)(const void*)(ar + kt * 32 + kg * 8);
        af[kt] = rok ? v : (bf16x8)(short)0;
    }
    // per-lane output rows are rbase+kg*4+0..3 for all col tiles; hoist dinv
    float4 dv4 = {1.f, 1.f, 1.f, 1.f};
    if (EPI == 0) dv4 = *(const float4*)(dinv + rbase + kg * 4);
    __syncthreads();

    int swz = (m16 & 7) << 3;
#pragma unroll
    for (int np = 0; np < 4; np++) {
        int nt0 = np * 2, nt1 = np * 2 + 1;
        f32x4 acc0 = {0.f, 0.f, 0.f, 0.f};
        f32x4 acc1 = {0.f, 0.f, 0.f, 0.f};
#pragma unroll
        for (int kt = 0; kt < 4; kt++) {
            int i0 = (((nt0 * 16 + m16) * 128) + kt * 32 + kg * 8) ^ swz;
            int i1 = (((nt1 * 16 + m16) * 128) + kt * 32 + kg * 8) ^ swz;
            bf16x8 bh0 = *(const bf16x8*)(const void*)&Wlds[i0];
            bf16x8 bl0 = *(const bf16x8*)(const void*)&Wlds[16384 + i0];
            bf16x8 bh1 = *(const bf16x8*)(const void*)&Wlds[i1];
            bf16x8 bl1 = *(const bf16x8*)(const void*)&Wlds[16384 + i1];
            acc0 = __builtin_amdgcn_mfma_f32_16x16x32_bf16(af[kt], bh0, acc0, 0, 0, 0);
            acc1 = __builtin_amdgcn_mfma_f32_16x16x32_bf16(af[kt], bh1, acc1, 0, 0, 0);
            acc0 = __builtin_amdgcn_mfma_f32_16x16x32_bf16(af[kt], bl0, acc0, 0, 0, 0);
            acc1 = __builtin_amdgcn_mfma_f32_16x16x32_bf16(af[kt], bl1, acc1, 0, 0, 0);
        }
#pragma unroll
        for (int half = 0; half < 2; half++) {
            int nt = half ? nt1 : nt0;
            const f32x4& acc = half ? acc1 : acc0;
            int n0 = nt * 16 + m16;
            if (EPI == 0) {
                float b = ba[n0];
#pragma unroll
                for (int j = 0; j < 4; j++) {
                    int r = rbase + kg * 4 + j;
                    if (r < M) {
                        float v = fmaxf(acc[j] + b, 0.f) * dv4[j];
                        H[(size_t)r * 128 + n0] = rne_bf16(v);
                    }
                }
            } else {
                bool is_mu = (n0 < 64);
                int c = is_mu ? n0 : (n0 - 64);
                float b = is_mu ? ba[c] : bb[c];
                size_t obase = is_mu ? 0 : (size_t)N_NODES * 64;
#pragma unroll
                for (int j = 0; j < 4; j++) {
                    int r = rbase + kg * 4 + j;
                    if (r < M) out[obase + (size_t)r * 64 + c] = acc[j] + b;
                }
            }
        }
    }
}

// ---------------------------------------------------------------------------
extern "C" void kernel_launch(void* const* d_in, const int* in_sizes, int n_in,
                              void* d_out, int out_size, void* d_ws, size_t ws_size,
                              hipStream_t stream) {
    const float* x    = (const float*)d_in[0];
    const int*   ei   = (const int*)d_in[1];
    const float* W1   = (const float*)d_in[2];
    const float* b1   = (const float*)d_in[3];
    const float* Wmu  = (const float*)d_in[4];
    const float* bmu  = (const float*)d_in[5];
    const float* Wlog = (const float*)d_in[6];
    const float* blog = (const float*)d_in[7];
    float* out = (float*)d_out;

    const int N = N_NODES;
    const int E = in_sizes[1] / 2;
    const int Emax = E + 3 * N;   // CSR with 4-padding slack
    const int* src = ei;
    const int* dst = ei + E;

    auto align256 = [](size_t v) { return (v + 255) & ~(size_t)255; };
    char* ws = (char*)d_ws;
    size_t off = 0;
    int*   counts  = (int*)(ws + off);  off += align256((size_t)NPAD * 4);
    int*   offsets = (int*)(ws + off);  off += align256((size_t)NPAD * 4);
    int*   local   = (int*)(ws + off);  off += align256((size_t)NPAD * 4);
    int*   bsums   = (int*)(ws + off);  off += align256(256 * 4);
    float* dinv    = (float*)(ws + off); off += align256((size_t)NPAD * 4);
    int*   rank    = (int*)(ws + off);  off += align256((size_t)E * 4);
    int*   csr_src = (int*)(ws + off);  off += align256((size_t)Emax * 4);
    unsigned short* xb    = (unsigned short*)(ws + off); off += align256((size_t)(N + 1) * FDIM * 2);
    unsigned short* Hb    = (unsigned short*)(ws + off); off += align256((size_t)(N + 1) * FDIM * 2);
    unsigned short* Ag    = (unsigned short*)(ws + off); off += align256((size_t)N * FDIM * 2);
    unsigned short* W1thi = (unsigned short*)(ws + off); off += align256(128 * 128 * 2);
    unsigned short* W1tlo = (unsigned short*)(ws + off); off += align256(128 * 128 * 2);
    unsigned short* Wcthi = (unsigned short*)(ws + off); off += align256(128 * 128 * 2);
    unsigned short* Wctlo = (unsigned short*)(ws + off); off += align256(128 * 128 * 2);

    // 1. zero counts + W split/transpose (fused, independent halves)
    zero_cvtw_kernel<<<SCAN_NB + 64, 256, 0, stream>>>((int4*)counts, W1, Wmu, Wlog,
                                                       W1thi, W1tlo, Wcthi, Wctlo);
    // 2. CSR count + rank
    count_kernel<<<(E + 255) / 256, 256, 0, stream>>>(dst, counts, rank, E);
    // 3. local scan (padded) + dinv
    scan_local_kernel<<<SCAN_NB, 256, 0, stream>>>(counts, local, bsums, dinv);
    // 4. offsets + pad sentinels + zero sentinel rows
    scan_add_kernel<<<SCAN_NB, 256, 0, stream>>>(local, bsums, counts, offsets,
                                                 csr_src, xb, Hb);
    // 5. scatter + cvt_x (fused)
    {
        int scb = (E + 255) / 256;
        int cvb = (N * FDIM / 4 + 255) / 256;
        scatter_cvtx_kernel<<<scb + cvb, 256, 0, stream>>>(src, dst, rank, offsets,
                                                           csr_src, E, scb,
                                                           x, dinv, xb, N * FDIM / 4);
    }
    // 6. agg1: dv*(xs_v + sum xs_s) -> single bf16
    agg_bf16_kernel<<<(N + 15) / 16, 256, 0, stream>>>(xb, offsets, csr_src, dinv, Ag, N);
    // 7. Hb = bf16(dinv * relu((Ax) @ W1 + b1))
    mfma_gemm_kernel<0><<<(N + 127) / 128, 512, 0, stream>>>(Ag, W1thi, W1tlo,
                                                             b1, nullptr, dinv, Hb, nullptr, N);
    // 8. agg2: dv*(hs_v + sum hs_s) -> single bf16
    agg_bf16_kernel<<<(N + 15) / 16, 256, 0, stream>>>(Hb, offsets, csr_src, dinv, Ag, N);
    // 9. [mu | logstd] = (Ah) @ [Wmu|Wlog] + bias -> d_out
    mfma_gemm_kernel<1><<<(N + 127) / 128, 512, 0, stream>>>(Ag, Wcthi, Wctlo,
                                                             bmu, blog, nullptr, nullptr, out, N);
}